// Round 10
// baseline (435.039 us; speedup 1.0000x reference)
//
#include <hip/hip_runtime.h>
#include <hip/hip_bf16.h>
#include <hip/hip_fp16.h>
#include <math.h>

// ---------------------------------------------------------------------------
// 2-layer GAT (PyG GATConv, concat=False, add_self_loops=True) on MI355X.
// R10: gemm_hist epilogue writes Hb as ONE uint4 (16B) store per lane-pair
// (shfl-xor head exchange) instead of 4x 2-byte scattered stores (was 4.4x
// write amplification); KC=32 halves LDS -> 5 blocks/CU (was 3).
// ---------------------------------------------------------------------------

__device__ __forceinline__ float lrelu(float x) { return x > 0.f ? x : 0.2f * x; }

// Monotone float<->uint encoding for atomicMax over signed floats.
// fenc(-FLT_MAX) > 0, so memset-0 acts as a -inf sentinel.
__device__ __forceinline__ unsigned int fenc(float f) {
    unsigned int u = __float_as_uint(f);
    return (u & 0x80000000u) ? ~u : (u | 0x80000000u);
}
__device__ __forceinline__ float fdec(unsigned int e) {
    unsigned int u = (e & 0x80000000u) ? (e & 0x7FFFFFFFu) : ~e;
    return __uint_as_float(u);
}

// bf16 round-to-nearest-even pack/unpack
__device__ __forceinline__ unsigned short f2bf(float x) {
    unsigned u = __float_as_uint(x);
    return (unsigned short)((u + 0x7FFFu + ((u >> 16) & 1u)) >> 16);
}
__device__ __forceinline__ float bflo(unsigned w) { return __uint_as_float(w << 16); }
__device__ __forceinline__ float bfhi(unsigned w) { return __uint_as_float(w & 0xFFFF0000u); }

// fp16 pack/unpack
__device__ __forceinline__ unsigned pack_h2(float a, float b) {
    const __half2 h = __float22half2_rn(make_float2(a, b));
    return *(const unsigned*)&h;
}
__device__ __forceinline__ float2 unpack_h2(unsigned w) {
    __half2 h = *(const __half2*)&w;
    return __half22float2(h);
}

// ---------------- hierarchical scan (CSR rowptr + cursor) ----------------
__global__ __launch_bounds__(256) void scan_part(const int* __restrict__ cnt,
                                                 int* __restrict__ bsum, int n) {
    __shared__ int red[256];
    const int t = threadIdx.x;
    const int i = blockIdx.x * 256 + t;
    red[t] = (i < n) ? cnt[i] : 0;
    __syncthreads();
    for (int o = 128; o > 0; o >>= 1) {
        if (t < o) red[t] += red[t + o];
        __syncthreads();
    }
    if (t == 0) bsum[blockIdx.x] = red[0];
}

__global__ __launch_bounds__(256) void scan_mid(const int* __restrict__ bsum,
                                                int* __restrict__ boff, int nb,
                                                int* __restrict__ rowptr, int n) {
    __shared__ int s[256];
    const int t = threadIdx.x;
    const int v = (t < nb) ? bsum[t] : 0;
    s[t] = v;
    __syncthreads();
    for (int o = 1; o < 256; o <<= 1) {
        const int u = (t >= o) ? s[t - o] : 0;
        __syncthreads();
        s[t] += u;
        __syncthreads();
    }
    if (t < nb) boff[t] = s[t] - v;   // exclusive block offset
    if (t == 255) rowptr[n] = s[255]; // total
}

__global__ __launch_bounds__(256) void scan_final(const int* __restrict__ cnt,
                                                  const int* __restrict__ boff,
                                                  int* __restrict__ rowptr,
                                                  int* __restrict__ cursor, int n) {
    __shared__ int s[256];
    const int t = threadIdx.x;
    const int i = blockIdx.x * 256 + t;
    const int v = (i < n) ? cnt[i] : 0;
    s[t] = v;
    __syncthreads();
    for (int o = 1; o < 256; o <<= 1) {
        const int u = (t >= o) ? s[t - o] : 0;
        __syncthreads();
        s[t] += u;
        __syncthreads();
    }
    if (i < n) {
        const int ex = boff[blockIdx.x] + s[t] - v;
        rowptr[i] = ex;
        cursor[i] = ex;
    }
}

// ---------------- bucketed scatter (int4-vectorized, single u64 store) -----
// Bucket b handled only by blocks with blockIdx%8==b (XCD-affine dispatch).
// Record: low32 = src*16, high32 = dst*16 (byte offsets into 16B-row tables).
__global__ __launch_bounds__(256) void scatter_kernel(
    const int* __restrict__ src, const int* __restrict__ dst,
    int* __restrict__ cursor, unsigned long long* __restrict__ sd,
    int E, int npb) {
    const int b = blockIdx.x & 7;
    const int gb = blockIdx.x >> 3;
    const int nbl = gridDim.x >> 3;
    const int lo = b * npb, hi = lo + npb;
    const int E4 = E >> 2;
    const int4* dst4 = (const int4*)dst;
    const int4* src4 = (const int4*)src;
    for (int i = gb * blockDim.x + threadIdx.x; i < E4; i += nbl * blockDim.x) {
        const int4 d = dst4[i];
        const int4 s = src4[i];
        if (d.x >= lo && d.x < hi) {
            const int p = atomicAdd(&cursor[d.x], 1);
            sd[p] = ((unsigned long long)(unsigned)(d.x << 4) << 32) | (unsigned)(s.x << 4);
        }
        if (d.y >= lo && d.y < hi) {
            const int p = atomicAdd(&cursor[d.y], 1);
            sd[p] = ((unsigned long long)(unsigned)(d.y << 4) << 32) | (unsigned)(s.y << 4);
        }
        if (d.z >= lo && d.z < hi) {
            const int p = atomicAdd(&cursor[d.z], 1);
            sd[p] = ((unsigned long long)(unsigned)(d.z << 4) << 32) | (unsigned)(s.z << 4);
        }
        if (d.w >= lo && d.w < hi) {
            const int p = atomicAdd(&cursor[d.w], 1);
            sd[p] = ((unsigned long long)(unsigned)(d.w << 4) << 32) | (unsigned)(s.w << 4);
        }
    }
    if (blockIdx.x == 0 && threadIdx.x < (E & 3)) {
        const int i = (E4 << 2) + threadIdx.x;
        const int d = dst[i];
        if (d >= lo && d < hi) {
            const int p = atomicAdd(&cursor[d], 1);
            sd[p] = ((unsigned long long)(unsigned)(d << 4) << 32) | (unsigned)(src[i] << 4);
        }
    }
}

// ---------------- per-edge softmax weights (fp16 pairs, u64 record) --------
// wq[i] = u64: low dword = half2(q_pos0,q_pos1), high dword = half2(q_pos2,q_pos3).
__global__ __launch_bounds__(256) void edge_w_kernel(
    const unsigned long long* __restrict__ sd,
    const float* __restrict__ asrc, const float* __restrict__ adst,
    const unsigned int* __restrict__ gmax, unsigned long long* __restrict__ wq,
    int Etot) {
    const char* aB = (const char*)asrc;
    const char* dB = (const char*)adst;
    const float g0 = fdec(gmax[0]), g1 = fdec(gmax[1]);
    const float g2 = fdec(gmax[2]), g3 = fdec(gmax[3]);
    for (int i = blockIdx.x * blockDim.x + threadIdx.x; i < Etot;
         i += gridDim.x * blockDim.x) {
        const unsigned long long rec = __builtin_nontemporal_load(&sd[i]);
        const unsigned s16 = (unsigned)rec;
        const unsigned d16 = (unsigned)(rec >> 32);
        const float4 as = *(const float4*)(aB + s16);
        const float4 ad = *(const float4*)(dB + d16);
        const float q0 = __expf(lrelu(as.x + ad.x) - lrelu(g0 + ad.x));
        const float q1 = __expf(lrelu(as.y + ad.y) - lrelu(g1 + ad.y));
        const float q2 = __expf(lrelu(as.z + ad.z) - lrelu(g2 + ad.z));
        const float q3 = __expf(lrelu(as.w + ad.w) - lrelu(g3 + ad.w));
        const unsigned lo = pack_h2(q0, q1);
        const unsigned hi = pack_h2(q2, q3);
        const unsigned long long out = ((unsigned long long)hi << 32) | lo;
        __builtin_nontemporal_store(out, &wq[i]);
    }
}

// ---------------- GEMM + alpha (+ fused hist + global head max) ----------------
// Hb layout (bf16): u16 idx = row*128 + (head&1)*64 + f*2 + (head>>1)
//   -> dword f of half (head&1) = [low: head hp, high: head hp+2].
// Epilogue: shfl-xor(16) exchanges acc with partner head (head^2); head<2
// lanes store one uint4 (16B) covering f=fc..fc+3 for both heads.
// asrc/adst layout: [row*4 + pos], pos(head) = [0,2,1,3] interleave.
template <int K>
__global__ __launch_bounds__(256) void gemm_hist(
    const float* __restrict__ X, const float* __restrict__ W,
    const float* __restrict__ AttS, const float* __restrict__ AttD,
    unsigned short* __restrict__ Hb, float* __restrict__ asrc, float* __restrict__ adst,
    unsigned int* __restrict__ gmax, int n, int gemmGrid,
    const int* __restrict__ dst, int* __restrict__ cnt, int E) {
    constexpr int KC = 32;
    __shared__ __align__(16) float Ws[KC * 128];
    __shared__ __align__(16) float Xs[32 * K];
    __shared__ unsigned int smax[4];
    const int tid = threadIdx.x;

    if (blockIdx.x >= gemmGrid) {
        // ---- hist role ----
        const int hb = blockIdx.x - gemmGrid;
        const int histBlocks = gridDim.x - gemmGrid;
        const int E4 = E >> 2;
        const int4* dst4 = (const int4*)dst;
        for (int i = hb * blockDim.x + tid; i < E4; i += histBlocks * blockDim.x) {
            const int4 d = dst4[i];
            atomicAdd(&cnt[d.x], 1);
            atomicAdd(&cnt[d.y], 1);
            atomicAdd(&cnt[d.z], 1);
            atomicAdd(&cnt[d.w], 1);
        }
        if (hb == 0 && tid < (E & 3)) atomicAdd(&cnt[dst[(E4 << 2) + tid]], 1);
        return;
    }

    // ---- gemm role ----
    const int r = tid >> 5;          // row-in-batch 0..7
    const int sub = tid & 31;
    const int c0 = sub * 4;          // output col base (0..124)
    const int head = sub >> 3;       // 0..3
    const int pos = ((head & 1) << 1) | (head >> 1);  // [0,2,1,3] order
    const int fc = (sub & 7) * 4;    // feat-in-head base
    const int rowBase = blockIdx.x * 32;

    if (tid < 4) smax[tid] = 0u;
    {
        const float4* X4 = (const float4*)X;
        float4* Xs4 = (float4*)Xs;
        const int K4 = K / 4;
        for (int i = tid; i < 32 * K4; i += 256) {
            int rr = rowBase + i / K4;
            Xs4[i] = (rr < n) ? X4[(size_t)rr * K4 + (i % K4)] : make_float4(0.f, 0.f, 0.f, 0.f);
        }
    }

    float acc[4][4] = {};
    for (int kt = 0; kt < K; kt += KC) {
        __syncthreads();
        {
            const float4* W4 = (const float4*)(W + kt * 128);
            float4* Ws4 = (float4*)Ws;
            for (int i = tid; i < KC * 32; i += 256) Ws4[i] = W4[i];
        }
        __syncthreads();
        for (int k = 0; k < KC; ++k) {
            const float4 wv = *(const float4*)&Ws[k * 128 + c0];
#pragma unroll
            for (int b = 0; b < 4; ++b) {
                float xv = Xs[(b * 8 + r) * K + kt + k];
                acc[b][0] = fmaf(xv, wv.x, acc[b][0]);
                acc[b][1] = fmaf(xv, wv.y, acc[b][1]);
                acc[b][2] = fmaf(xv, wv.z, acc[b][2]);
                acc[b][3] = fmaf(xv, wv.w, acc[b][3]);
            }
        }
    }

    float a_s[4], a_d[4];
#pragma unroll
    for (int j = 0; j < 4; ++j) {
        a_s[j] = AttS[head * 32 + fc + j];
        a_d[j] = AttD[head * 32 + fc + j];
    }
#pragma unroll
    for (int b = 0; b < 4; ++b) {
        const int row = rowBase + b * 8 + r;
        // exchange with partner head (head^2): lane tid^16 (same r, same fc)
        const float p0 = __shfl_xor(acc[b][0], 16);
        const float p1 = __shfl_xor(acc[b][1], 16);
        const float p2 = __shfl_xor(acc[b][2], 16);
        const float p3 = __shfl_xor(acc[b][3], 16);
        if (row < n) {
            if (head < 2) {
                uint4 o;
                o.x = (unsigned)f2bf(acc[b][0]) | ((unsigned)f2bf(p0) << 16);
                o.y = (unsigned)f2bf(acc[b][1]) | ((unsigned)f2bf(p1) << 16);
                o.z = (unsigned)f2bf(acc[b][2]) | ((unsigned)f2bf(p2) << 16);
                o.w = (unsigned)f2bf(acc[b][3]) | ((unsigned)f2bf(p3) << 16);
                *(uint4*)((char*)Hb + (size_t)row * 256 + head * 128 + fc * 4) = o;
            }
            float ps = acc[b][0] * a_s[0] + acc[b][1] * a_s[1] +
                       acc[b][2] * a_s[2] + acc[b][3] * a_s[3];
            float pd = acc[b][0] * a_d[0] + acc[b][1] * a_d[1] +
                       acc[b][2] * a_d[2] + acc[b][3] * a_d[3];
#pragma unroll
            for (int msk = 1; msk < 8; msk <<= 1) {
                ps += __shfl_xor(ps, msk);
                pd += __shfl_xor(pd, msk);
            }
            if ((sub & 7) == 0) {
                asrc[row * 4 + pos] = ps;
                adst[row * 4 + pos] = pd;
                atomicMax(&smax[pos], fenc(ps));
            }
        }
    }
    __syncthreads();
    if (tid < 4) atomicMax(&gmax[tid], smax[tid]);
}

// ---------------- per-node aggregate (weights precomputed) ----------------
// One node per 64-lane group; lane = hp*32 + f owns heads (hp, hp+2) -> one
// Hb dword. Per edge: broadcast sd + weight dword, 1 gather, 2 fma.
__global__ __launch_bounds__(256) void node_kernel(
    const int* __restrict__ rowptr, const unsigned long long* __restrict__ sd,
    const unsigned short* __restrict__ Hb, const float* __restrict__ asrc,
    const float* __restrict__ adst, const unsigned int* __restrict__ gmax,
    const unsigned long long* __restrict__ wq, const float* __restrict__ bias,
    float* __restrict__ outp, int n, int apply_elu) {
    const int node = blockIdx.x * 4 + (threadIdx.x >> 6);
    if (node >= n) return;
    const int lane = threadIdx.x & 63;
    const unsigned f = lane & 31;
    const unsigned hp = lane >> 5;            // 0/1
    const unsigned hp8 = hp * 8;              // byte off into asrc/adst row (16B)
    const unsigned hp4 = hp * 4;              // byte off into wq record (8B)
    const unsigned hpf = hp * 128 + f * 4;    // byte off into Hb row (256B)
    const unsigned node16 = (unsigned)node * 16;
    const char* aB = (const char*)asrc;
    const char* dB = (const char*)adst;
    const char* hB = (const char*)Hb;
    const char* wB = (const char*)wq;

    const int beg = rowptr[node], end = rowptr[node + 1];
    const float2 ad01 = *(const float2*)(dB + node16 + hp8);
    const float2 M01 = make_float2(lrelu(fdec(gmax[hp * 2]) + ad01.x),
                                   lrelu(fdec(gmax[hp * 2 + 1]) + ad01.y));

    // self loop (fp32, same M as edge weights)
    const float2 aself = *(const float2*)(aB + node16 + hp8);
    float2 q = make_float2(__expf(lrelu(aself.x + ad01.x) - M01.x),
                           __expf(lrelu(aself.y + ad01.y) - M01.y));
    float2 s01 = q;
    const unsigned wSelf = *(const unsigned*)(hB + (node16 << 4) + hpf);
    float2 acc01 = make_float2(q.x * bflo(wSelf), q.y * bfhi(wSelf));

    int i = beg;
    for (; i + 16 <= end; i += 16) {
        unsigned sx[16];
#pragma unroll
        for (int u = 0; u < 16; ++u)
            sx[u] = (unsigned)__builtin_nontemporal_load(&sd[i + u]);  // low32 = s*16
        unsigned wv[16];
#pragma unroll
        for (int u = 0; u < 16; ++u)
            wv[u] = *(const unsigned*)(wB + (((unsigned)(i + u)) << 3) + hp4);
        unsigned w[16];
#pragma unroll
        for (int u = 0; u < 16; ++u) w[u] = *(const unsigned*)(hB + (sx[u] << 4) + hpf);
#pragma unroll
        for (int u = 0; u < 16; ++u) {
            const float2 qf = unpack_h2(wv[u]);
            s01.x += qf.x; s01.y += qf.y;
            acc01.x = fmaf(qf.x, bflo(w[u]), acc01.x);
            acc01.y = fmaf(qf.y, bfhi(w[u]), acc01.y);
        }
    }
    for (; i + 4 <= end; i += 4) {
        unsigned sx[4];
#pragma unroll
        for (int u = 0; u < 4; ++u)
            sx[u] = (unsigned)__builtin_nontemporal_load(&sd[i + u]);
        unsigned wv[4];
#pragma unroll
        for (int u = 0; u < 4; ++u)
            wv[u] = *(const unsigned*)(wB + (((unsigned)(i + u)) << 3) + hp4);
        unsigned w[4];
#pragma unroll
        for (int u = 0; u < 4; ++u) w[u] = *(const unsigned*)(hB + (sx[u] << 4) + hpf);
#pragma unroll
        for (int u = 0; u < 4; ++u) {
            const float2 qf = unpack_h2(wv[u]);
            s01.x += qf.x; s01.y += qf.y;
            acc01.x = fmaf(qf.x, bflo(w[u]), acc01.x);
            acc01.y = fmaf(qf.y, bfhi(w[u]), acc01.y);
        }
    }
    for (; i < end; ++i) {
        const unsigned sx = (unsigned)__builtin_nontemporal_load(&sd[i]);
        const unsigned wh = *(const unsigned*)(wB + (((unsigned)i) << 3) + hp4);
        const unsigned wv = *(const unsigned*)(hB + (sx << 4) + hpf);
        const float2 qf = unpack_h2(wh);
        s01.x += qf.x; s01.y += qf.y;
        acc01.x = fmaf(qf.x, bflo(wv), acc01.x);
        acc01.y = fmaf(qf.y, bfhi(wv), acc01.y);
    }

    float v = acc01.x / s01.x + acc01.y / s01.y;
    v += __shfl_xor(v, 32);     // add the other head pair
    v = v * 0.25f + bias[f];
    if (apply_elu) v = (v > 0.f) ? v : (__expf(v) - 1.f);
    if (lane < 32) outp[(size_t)node * 32 + f] = v;
}

// ---------------- launch ----------------

extern "C" void kernel_launch(void* const* d_in, const int* in_sizes, int n_in,
                              void* d_out, int out_size, void* d_ws, size_t ws_size,
                              hipStream_t stream) {
    const int N = in_sizes[0] / 128;
    const int E = in_sizes[1] / 2;
    const float* x = (const float*)d_in[0];
    const int* ei = (const int*)d_in[1];
    const float* W1 = (const float*)d_in[2];
    const float* atS1 = (const float*)d_in[3];
    const float* atD1 = (const float*)d_in[4];
    const float* b1 = (const float*)d_in[5];
    const float* W2 = (const float*)d_in[6];
    const float* atS2 = (const float*)d_in[7];
    const float* atD2 = (const float*)d_in[8];
    const float* b2 = (const float*)d_in[9];
    float* out = (float*)d_out;

    char* ws = (char*)d_ws;
    size_t off = 0;
    auto alloc = [&](size_t bytes) {
        void* p = ws + off;
        off = (off + bytes + 255) & ~(size_t)255;
        return p;
    };
    int* cnt = (int*)alloc((size_t)N * 4);
    unsigned int* gmax = (unsigned int*)alloc(8 * sizeof(unsigned int)); // [layer][pos]
    const size_t zeroBytes = off;  // cnt + gmax zeroed in one memset
    int* rowptr = (int*)alloc((size_t)(N + 1) * 4);
    int* cursor = (int*)alloc((size_t)N * 4);
    int* bsum = (int*)alloc(256 * 4);
    int* boff = (int*)alloc(256 * 4);
    unsigned long long* sd = (unsigned long long*)alloc((size_t)E * 8);
    unsigned long long* wq = (unsigned long long*)alloc((size_t)E * 8);
    unsigned short* hb = (unsigned short*)alloc((size_t)N * 128 * 2);  // packed bf16
    float* av_s = (float*)alloc((size_t)N * 4 * 4);
    float* av_d = (float*)alloc((size_t)N * 4 * 4);
    float* x2 = (float*)alloc((size_t)N * 32 * 4);

    const int* e_src = ei;
    const int* e_dst = ei + E;

    const int gemmGrid = (N + 31) / 32;
    const int histGrid = 1024;
    const int nodeGrid = (N + 3) / 4;
    const int npb = (N + 7) / 8;
    const int scanGrid = (N + 255) / 256;   // must be <= 256

    (void)hipMemsetAsync(cnt, 0, zeroBytes, stream);

    // layer 1
    gemm_hist<128><<<gemmGrid + histGrid, 256, 0, stream>>>(
        x, W1, atS1, atD1, hb, av_s, av_d, gmax, N, gemmGrid, e_dst, cnt, E);
    scan_part<<<scanGrid, 256, 0, stream>>>(cnt, bsum, N);
    scan_mid<<<1, 256, 0, stream>>>(bsum, boff, scanGrid, rowptr, N);
    scan_final<<<scanGrid, 256, 0, stream>>>(cnt, boff, rowptr, cursor, N);
    scatter_kernel<<<2048, 256, 0, stream>>>(e_src, e_dst, cursor, sd, E, npb);
    edge_w_kernel<<<2048, 256, 0, stream>>>(sd, av_s, av_d, gmax, wq, E);
    node_kernel<<<nodeGrid, 256, 0, stream>>>(rowptr, sd, hb, av_s, av_d, gmax,
                                              wq, b1, x2, N, 1);
    // layer 2
    gemm_hist<32><<<gemmGrid, 256, 0, stream>>>(
        x2, W2, atS2, atD2, hb, av_s, av_d, gmax + 4, N, gemmGrid, e_dst, cnt, E);
    edge_w_kernel<<<2048, 256, 0, stream>>>(sd, av_s, av_d, gmax + 4, wq, E);
    node_kernel<<<nodeGrid, 256, 0, stream>>>(rowptr, sd, hb, av_s, av_d, gmax + 4,
                                              wq, b2, out, N, 0);
}

// Round 11
// 426.927 us; speedup vs baseline: 1.0190x; 1.0190x over previous
//
#include <hip/hip_runtime.h>
#include <hip/hip_bf16.h>
#include <hip/hip_fp16.h>
#include <math.h>

// ---------------------------------------------------------------------------
// 2-layer GAT (PyG GATConv, concat=False, add_self_loops=True) on MI355X.
// R11: GEMM restructured for throughput — 64 rows/block, acc[8][4] register
// tile, float4 LDS reads for BOTH operands, k unrolled x4 (12 ds_read_b128
// per 128 FMAs). Everything else as R10.
// ---------------------------------------------------------------------------

__device__ __forceinline__ float lrelu(float x) { return x > 0.f ? x : 0.2f * x; }

__device__ __forceinline__ unsigned int fenc(float f) {
    unsigned int u = __float_as_uint(f);
    return (u & 0x80000000u) ? ~u : (u | 0x80000000u);
}
__device__ __forceinline__ float fdec(unsigned int e) {
    unsigned int u = (e & 0x80000000u) ? (e & 0x7FFFFFFFu) : ~e;
    return __uint_as_float(u);
}

__device__ __forceinline__ unsigned short f2bf(float x) {
    unsigned u = __float_as_uint(x);
    return (unsigned short)((u + 0x7FFFu + ((u >> 16) & 1u)) >> 16);
}
__device__ __forceinline__ float bflo(unsigned w) { return __uint_as_float(w << 16); }
__device__ __forceinline__ float bfhi(unsigned w) { return __uint_as_float(w & 0xFFFF0000u); }

__device__ __forceinline__ unsigned pack_h2(float a, float b) {
    const __half2 h = __float22half2_rn(make_float2(a, b));
    return *(const unsigned*)&h;
}
__device__ __forceinline__ float2 unpack_h2(unsigned w) {
    __half2 h = *(const __half2*)&w;
    return __half22float2(h);
}

// ---------------- hierarchical scan (CSR rowptr + cursor) ----------------
__global__ __launch_bounds__(256) void scan_part(const int* __restrict__ cnt,
                                                 int* __restrict__ bsum, int n) {
    __shared__ int red[256];
    const int t = threadIdx.x;
    const int i = blockIdx.x * 256 + t;
    red[t] = (i < n) ? cnt[i] : 0;
    __syncthreads();
    for (int o = 128; o > 0; o >>= 1) {
        if (t < o) red[t] += red[t + o];
        __syncthreads();
    }
    if (t == 0) bsum[blockIdx.x] = red[0];
}

__global__ __launch_bounds__(256) void scan_mid(const int* __restrict__ bsum,
                                                int* __restrict__ boff, int nb,
                                                int* __restrict__ rowptr, int n) {
    __shared__ int s[256];
    const int t = threadIdx.x;
    const int v = (t < nb) ? bsum[t] : 0;
    s[t] = v;
    __syncthreads();
    for (int o = 1; o < 256; o <<= 1) {
        const int u = (t >= o) ? s[t - o] : 0;
        __syncthreads();
        s[t] += u;
        __syncthreads();
    }
    if (t < nb) boff[t] = s[t] - v;   // exclusive block offset
    if (t == 255) rowptr[n] = s[255]; // total
}

__global__ __launch_bounds__(256) void scan_final(const int* __restrict__ cnt,
                                                  const int* __restrict__ boff,
                                                  int* __restrict__ rowptr,
                                                  int* __restrict__ cursor, int n) {
    __shared__ int s[256];
    const int t = threadIdx.x;
    const int i = blockIdx.x * 256 + t;
    const int v = (i < n) ? cnt[i] : 0;
    s[t] = v;
    __syncthreads();
    for (int o = 1; o < 256; o <<= 1) {
        const int u = (t >= o) ? s[t - o] : 0;
        __syncthreads();
        s[t] += u;
        __syncthreads();
    }
    if (i < n) {
        const int ex = boff[blockIdx.x] + s[t] - v;
        rowptr[i] = ex;
        cursor[i] = ex;
    }
}

// ---------------- bucketed scatter (int4-vectorized, single u64 store) -----
__global__ __launch_bounds__(256) void scatter_kernel(
    const int* __restrict__ src, const int* __restrict__ dst,
    int* __restrict__ cursor, unsigned long long* __restrict__ sd,
    int E, int npb) {
    const int b = blockIdx.x & 7;
    const int gb = blockIdx.x >> 3;
    const int nbl = gridDim.x >> 3;
    const int lo = b * npb, hi = lo + npb;
    const int E4 = E >> 2;
    const int4* dst4 = (const int4*)dst;
    const int4* src4 = (const int4*)src;
    for (int i = gb * blockDim.x + threadIdx.x; i < E4; i += nbl * blockDim.x) {
        const int4 d = dst4[i];
        const int4 s = src4[i];
        if (d.x >= lo && d.x < hi) {
            const int p = atomicAdd(&cursor[d.x], 1);
            sd[p] = ((unsigned long long)(unsigned)(d.x << 4) << 32) | (unsigned)(s.x << 4);
        }
        if (d.y >= lo && d.y < hi) {
            const int p = atomicAdd(&cursor[d.y], 1);
            sd[p] = ((unsigned long long)(unsigned)(d.y << 4) << 32) | (unsigned)(s.y << 4);
        }
        if (d.z >= lo && d.z < hi) {
            const int p = atomicAdd(&cursor[d.z], 1);
            sd[p] = ((unsigned long long)(unsigned)(d.z << 4) << 32) | (unsigned)(s.z << 4);
        }
        if (d.w >= lo && d.w < hi) {
            const int p = atomicAdd(&cursor[d.w], 1);
            sd[p] = ((unsigned long long)(unsigned)(d.w << 4) << 32) | (unsigned)(s.w << 4);
        }
    }
    if (blockIdx.x == 0 && threadIdx.x < (E & 3)) {
        const int i = (E4 << 2) + threadIdx.x;
        const int d = dst[i];
        if (d >= lo && d < hi) {
            const int p = atomicAdd(&cursor[d], 1);
            sd[p] = ((unsigned long long)(unsigned)(d << 4) << 32) | (unsigned)(src[i] << 4);
        }
    }
}

// ---------------- per-edge softmax weights (fp16 pairs, u64 record) --------
__global__ __launch_bounds__(256) void edge_w_kernel(
    const unsigned long long* __restrict__ sd,
    const float* __restrict__ asrc, const float* __restrict__ adst,
    const unsigned int* __restrict__ gmax, unsigned long long* __restrict__ wq,
    int Etot) {
    const char* aB = (const char*)asrc;
    const char* dB = (const char*)adst;
    const float g0 = fdec(gmax[0]), g1 = fdec(gmax[1]);
    const float g2 = fdec(gmax[2]), g3 = fdec(gmax[3]);
    for (int i = blockIdx.x * blockDim.x + threadIdx.x; i < Etot;
         i += gridDim.x * blockDim.x) {
        const unsigned long long rec = __builtin_nontemporal_load(&sd[i]);
        const unsigned s16 = (unsigned)rec;
        const unsigned d16 = (unsigned)(rec >> 32);
        const float4 as = *(const float4*)(aB + s16);
        const float4 ad = *(const float4*)(dB + d16);
        const float q0 = __expf(lrelu(as.x + ad.x) - lrelu(g0 + ad.x));
        const float q1 = __expf(lrelu(as.y + ad.y) - lrelu(g1 + ad.y));
        const float q2 = __expf(lrelu(as.z + ad.z) - lrelu(g2 + ad.z));
        const float q3 = __expf(lrelu(as.w + ad.w) - lrelu(g3 + ad.w));
        const unsigned lo = pack_h2(q0, q1);
        const unsigned hi = pack_h2(q2, q3);
        const unsigned long long out = ((unsigned long long)hi << 32) | lo;
        __builtin_nontemporal_store(out, &wq[i]);
    }
}

// ---------------- GEMM + alpha (+ fused hist + global head max) ------------
// 64 rows/block, 256 threads: r=tid>>5 (0..7), sub=tid&31 (col group).
// Thread computes rows {b*8+r, b=0..7} x cols {c0..c0+3}: acc[8][4].
// k unrolled x4: 12 ds_read_b128 per 128 FMAs.
// Hb layout (bf16): dword f of half (head&1) = [low: head hp, high: hp+2].
template <int K>
__global__ __launch_bounds__(256) void gemm_hist(
    const float* __restrict__ X, const float* __restrict__ W,
    const float* __restrict__ AttS, const float* __restrict__ AttD,
    unsigned short* __restrict__ Hb, float* __restrict__ asrc, float* __restrict__ adst,
    unsigned int* __restrict__ gmax, int n, int gemmGrid,
    const int* __restrict__ dst, int* __restrict__ cnt, int E) {
    constexpr int KC = 32;
    __shared__ __align__(16) float Ws[KC * 128];
    __shared__ __align__(16) float Xs[64 * K];
    __shared__ unsigned int smax[4];
    const int tid = threadIdx.x;

    if (blockIdx.x >= gemmGrid) {
        // ---- hist role ----
        const int hb = blockIdx.x - gemmGrid;
        const int histBlocks = gridDim.x - gemmGrid;
        const int E4 = E >> 2;
        const int4* dst4 = (const int4*)dst;
        for (int i = hb * blockDim.x + tid; i < E4; i += histBlocks * blockDim.x) {
            const int4 d = dst4[i];
            atomicAdd(&cnt[d.x], 1);
            atomicAdd(&cnt[d.y], 1);
            atomicAdd(&cnt[d.z], 1);
            atomicAdd(&cnt[d.w], 1);
        }
        if (hb == 0 && tid < (E & 3)) atomicAdd(&cnt[dst[(E4 << 2) + tid]], 1);
        return;
    }

    // ---- gemm role ----
    const int r = tid >> 5;          // row-in-batch 0..7
    const int sub = tid & 31;
    const int head = sub >> 3;       // 0..3
    const int pos = ((head & 1) << 1) | (head >> 1);  // [0,2,1,3] order
    const int fc = (sub & 7) * 4;    // feat-in-head base
    const int rowBase = blockIdx.x * 64;

    if (tid < 4) smax[tid] = 0u;
    {
        const float4* X4 = (const float4*)X;
        float4* Xs4 = (float4*)Xs;
        const int K4 = K / 4;
        for (int i = tid; i < 64 * K4; i += 256) {
            int rr = rowBase + i / K4;
            Xs4[i] = (rr < n) ? X4[(size_t)rr * K4 + (i % K4)] : make_float4(0.f, 0.f, 0.f, 0.f);
        }
    }

    float acc[8][4] = {};
    const float4* Ws4 = (const float4*)Ws;
    for (int kt = 0; kt < K; kt += KC) {
        __syncthreads();
        {
            const float4* W4 = (const float4*)(W + kt * 128);
            float4* WsS = (float4*)Ws;
#pragma unroll
            for (int i = 0; i < 4; ++i) WsS[tid + i * 256] = W4[tid + i * 256];
        }
        __syncthreads();
#pragma unroll
        for (int k = 0; k < KC; k += 4) {
            float4 wv[4];
#pragma unroll
            for (int j = 0; j < 4; ++j) wv[j] = Ws4[(k + j) * 32 + sub];
            float4 xv[8];
#pragma unroll
            for (int b = 0; b < 8; ++b)
                xv[b] = *(const float4*)&Xs[(b * 8 + r) * K + kt + k];
#pragma unroll
            for (int b = 0; b < 8; ++b) {
                acc[b][0] = fmaf(xv[b].x, wv[0].x, acc[b][0]);
                acc[b][1] = fmaf(xv[b].x, wv[0].y, acc[b][1]);
                acc[b][2] = fmaf(xv[b].x, wv[0].z, acc[b][2]);
                acc[b][3] = fmaf(xv[b].x, wv[0].w, acc[b][3]);
                acc[b][0] = fmaf(xv[b].y, wv[1].x, acc[b][0]);
                acc[b][1] = fmaf(xv[b].y, wv[1].y, acc[b][1]);
                acc[b][2] = fmaf(xv[b].y, wv[1].z, acc[b][2]);
                acc[b][3] = fmaf(xv[b].y, wv[1].w, acc[b][3]);
                acc[b][0] = fmaf(xv[b].z, wv[2].x, acc[b][0]);
                acc[b][1] = fmaf(xv[b].z, wv[2].y, acc[b][1]);
                acc[b][2] = fmaf(xv[b].z, wv[2].z, acc[b][2]);
                acc[b][3] = fmaf(xv[b].z, wv[2].w, acc[b][3]);
                acc[b][0] = fmaf(xv[b].w, wv[3].x, acc[b][0]);
                acc[b][1] = fmaf(xv[b].w, wv[3].y, acc[b][1]);
                acc[b][2] = fmaf(xv[b].w, wv[3].z, acc[b][2]);
                acc[b][3] = fmaf(xv[b].w, wv[3].w, acc[b][3]);
            }
        }
    }

    float a_s[4], a_d[4];
#pragma unroll
    for (int j = 0; j < 4; ++j) {
        a_s[j] = AttS[head * 32 + fc + j];
        a_d[j] = AttD[head * 32 + fc + j];
    }
#pragma unroll
    for (int b = 0; b < 8; ++b) {
        const int row = rowBase + b * 8 + r;
        const float p0 = __shfl_xor(acc[b][0], 16);
        const float p1 = __shfl_xor(acc[b][1], 16);
        const float p2 = __shfl_xor(acc[b][2], 16);
        const float p3 = __shfl_xor(acc[b][3], 16);
        if (row < n) {
            if (head < 2) {
                uint4 o;
                o.x = (unsigned)f2bf(acc[b][0]) | ((unsigned)f2bf(p0) << 16);
                o.y = (unsigned)f2bf(acc[b][1]) | ((unsigned)f2bf(p1) << 16);
                o.z = (unsigned)f2bf(acc[b][2]) | ((unsigned)f2bf(p2) << 16);
                o.w = (unsigned)f2bf(acc[b][3]) | ((unsigned)f2bf(p3) << 16);
                *(uint4*)((char*)Hb + (size_t)row * 256 + head * 128 + fc * 4) = o;
            }
            float ps = acc[b][0] * a_s[0] + acc[b][1] * a_s[1] +
                       acc[b][2] * a_s[2] + acc[b][3] * a_s[3];
            float pd = acc[b][0] * a_d[0] + acc[b][1] * a_d[1] +
                       acc[b][2] * a_d[2] + acc[b][3] * a_d[3];
#pragma unroll
            for (int msk = 1; msk < 8; msk <<= 1) {
                ps += __shfl_xor(ps, msk);
                pd += __shfl_xor(pd, msk);
            }
            if ((sub & 7) == 0) {
                asrc[row * 4 + pos] = ps;
                adst[row * 4 + pos] = pd;
                atomicMax(&smax[pos], fenc(ps));
            }
        }
    }
    __syncthreads();
    if (tid < 4) atomicMax(&gmax[tid], smax[tid]);
}

// ---------------- per-node aggregate (weights precomputed) ----------------
__global__ __launch_bounds__(256) void node_kernel(
    const int* __restrict__ rowptr, const unsigned long long* __restrict__ sd,
    const unsigned short* __restrict__ Hb, const float* __restrict__ asrc,
    const float* __restrict__ adst, const unsigned int* __restrict__ gmax,
    const unsigned long long* __restrict__ wq, const float* __restrict__ bias,
    float* __restrict__ outp, int n, int apply_elu) {
    const int node = blockIdx.x * 4 + (threadIdx.x >> 6);
    if (node >= n) return;
    const int lane = threadIdx.x & 63;
    const unsigned f = lane & 31;
    const unsigned hp = lane >> 5;            // 0/1
    const unsigned hp8 = hp * 8;              // byte off into asrc/adst row (16B)
    const unsigned hp4 = hp * 4;              // byte off into wq record (8B)
    const unsigned hpf = hp * 128 + f * 4;    // byte off into Hb row (256B)
    const unsigned node16 = (unsigned)node * 16;
    const char* aB = (const char*)asrc;
    const char* dB = (const char*)adst;
    const char* hB = (const char*)Hb;
    const char* wB = (const char*)wq;

    const int beg = rowptr[node], end = rowptr[node + 1];
    const float2 ad01 = *(const float2*)(dB + node16 + hp8);
    const float2 M01 = make_float2(lrelu(fdec(gmax[hp * 2]) + ad01.x),
                                   lrelu(fdec(gmax[hp * 2 + 1]) + ad01.y));

    const float2 aself = *(const float2*)(aB + node16 + hp8);
    float2 q = make_float2(__expf(lrelu(aself.x + ad01.x) - M01.x),
                           __expf(lrelu(aself.y + ad01.y) - M01.y));
    float2 s01 = q;
    const unsigned wSelf = *(const unsigned*)(hB + (node16 << 4) + hpf);
    float2 acc01 = make_float2(q.x * bflo(wSelf), q.y * bfhi(wSelf));

    int i = beg;
    for (; i + 16 <= end; i += 16) {
        unsigned sx[16];
#pragma unroll
        for (int u = 0; u < 16; ++u)
            sx[u] = (unsigned)__builtin_nontemporal_load(&sd[i + u]);  // low32 = s*16
        unsigned wv[16];
#pragma unroll
        for (int u = 0; u < 16; ++u)
            wv[u] = *(const unsigned*)(wB + (((unsigned)(i + u)) << 3) + hp4);
        unsigned w[16];
#pragma unroll
        for (int u = 0; u < 16; ++u) w[u] = *(const unsigned*)(hB + (sx[u] << 4) + hpf);
#pragma unroll
        for (int u = 0; u < 16; ++u) {
            const float2 qf = unpack_h2(wv[u]);
            s01.x += qf.x; s01.y += qf.y;
            acc01.x = fmaf(qf.x, bflo(w[u]), acc01.x);
            acc01.y = fmaf(qf.y, bfhi(w[u]), acc01.y);
        }
    }
    for (; i + 4 <= end; i += 4) {
        unsigned sx[4];
#pragma unroll
        for (int u = 0; u < 4; ++u)
            sx[u] = (unsigned)__builtin_nontemporal_load(&sd[i + u]);
        unsigned wv[4];
#pragma unroll
        for (int u = 0; u < 4; ++u)
            wv[u] = *(const unsigned*)(wB + (((unsigned)(i + u)) << 3) + hp4);
        unsigned w[4];
#pragma unroll
        for (int u = 0; u < 4; ++u) w[u] = *(const unsigned*)(hB + (sx[u] << 4) + hpf);
#pragma unroll
        for (int u = 0; u < 4; ++u) {
            const float2 qf = unpack_h2(wv[u]);
            s01.x += qf.x; s01.y += qf.y;
            acc01.x = fmaf(qf.x, bflo(w[u]), acc01.x);
            acc01.y = fmaf(qf.y, bfhi(w[u]), acc01.y);
        }
    }
    for (; i < end; ++i) {
        const unsigned sx = (unsigned)__builtin_nontemporal_load(&sd[i]);
        const unsigned wh = *(const unsigned*)(wB + (((unsigned)i) << 3) + hp4);
        const unsigned wv = *(const unsigned*)(hB + (sx << 4) + hpf);
        const float2 qf = unpack_h2(wh);
        s01.x += qf.x; s01.y += qf.y;
        acc01.x = fmaf(qf.x, bflo(wv), acc01.x);
        acc01.y = fmaf(qf.y, bfhi(wv), acc01.y);
    }

    float v = acc01.x / s01.x + acc01.y / s01.y;
    v += __shfl_xor(v, 32);     // add the other head pair
    v = v * 0.25f + bias[f];
    if (apply_elu) v = (v > 0.f) ? v : (__expf(v) - 1.f);
    if (lane < 32) outp[(size_t)node * 32 + f] = v;
}

// ---------------- launch ----------------

extern "C" void kernel_launch(void* const* d_in, const int* in_sizes, int n_in,
                              void* d_out, int out_size, void* d_ws, size_t ws_size,
                              hipStream_t stream) {
    const int N = in_sizes[0] / 128;
    const int E = in_sizes[1] / 2;
    const float* x = (const float*)d_in[0];
    const int* ei = (const int*)d_in[1];
    const float* W1 = (const float*)d_in[2];
    const float* atS1 = (const float*)d_in[3];
    const float* atD1 = (const float*)d_in[4];
    const float* b1 = (const float*)d_in[5];
    const float* W2 = (const float*)d_in[6];
    const float* atS2 = (const float*)d_in[7];
    const float* atD2 = (const float*)d_in[8];
    const float* b2 = (const float*)d_in[9];
    float* out = (float*)d_out;

    char* ws = (char*)d_ws;
    size_t off = 0;
    auto alloc = [&](size_t bytes) {
        void* p = ws + off;
        off = (off + bytes + 255) & ~(size_t)255;
        return p;
    };
    int* cnt = (int*)alloc((size_t)N * 4);
    unsigned int* gmax = (unsigned int*)alloc(8 * sizeof(unsigned int)); // [layer][pos]
    const size_t zeroBytes = off;  // cnt + gmax zeroed in one memset
    int* rowptr = (int*)alloc((size_t)(N + 1) * 4);
    int* cursor = (int*)alloc((size_t)N * 4);
    int* bsum = (int*)alloc(256 * 4);
    int* boff = (int*)alloc(256 * 4);
    unsigned long long* sd = (unsigned long long*)alloc((size_t)E * 8);
    unsigned long long* wq = (unsigned long long*)alloc((size_t)E * 8);
    unsigned short* hb = (unsigned short*)alloc((size_t)N * 128 * 2);  // packed bf16
    float* av_s = (float*)alloc((size_t)N * 4 * 4);
    float* av_d = (float*)alloc((size_t)N * 4 * 4);
    float* x2 = (float*)alloc((size_t)N * 32 * 4);

    const int* e_src = ei;
    const int* e_dst = ei + E;

    const int gemmGrid = (N + 63) / 64;
    const int histGrid = 1024;
    const int nodeGrid = (N + 3) / 4;
    const int npb = (N + 7) / 8;
    const int scanGrid = (N + 255) / 256;   // must be <= 256

    (void)hipMemsetAsync(cnt, 0, zeroBytes, stream);

    // layer 1
    gemm_hist<128><<<gemmGrid + histGrid, 256, 0, stream>>>(
        x, W1, atS1, atD1, hb, av_s, av_d, gmax, N, gemmGrid, e_dst, cnt, E);
    scan_part<<<scanGrid, 256, 0, stream>>>(cnt, bsum, N);
    scan_mid<<<1, 256, 0, stream>>>(bsum, boff, scanGrid, rowptr, N);
    scan_final<<<scanGrid, 256, 0, stream>>>(cnt, boff, rowptr, cursor, N);
    scatter_kernel<<<2048, 256, 0, stream>>>(e_src, e_dst, cursor, sd, E, npb);
    edge_w_kernel<<<2048, 256, 0, stream>>>(sd, av_s, av_d, gmax, wq, E);
    node_kernel<<<nodeGrid, 256, 0, stream>>>(rowptr, sd, hb, av_s, av_d, gmax,
                                              wq, b1, x2, N, 1);
    // layer 2
    gemm_hist<32><<<gemmGrid, 256, 0, stream>>>(
        x2, W2, atS2, atD2, hb, av_s, av_d, gmax + 4, N, gemmGrid, e_dst, cnt, E);
    edge_w_kernel<<<2048, 256, 0, stream>>>(sd, av_s, av_d, gmax + 4, wq, E);
    node_kernel<<<nodeGrid, 256, 0, stream>>>(rowptr, sd, hb, av_s, av_d, gmax + 4,
                                              wq, b2, out, N, 0);
}

// Round 12
// 373.191 us; speedup vs baseline: 1.1657x; 1.1440x over previous
//
#include <hip/hip_runtime.h>
#include <hip/hip_bf16.h>
#include <hip/hip_fp16.h>
#include <math.h>

// ---------------------------------------------------------------------------
// 2-layer GAT (PyG GATConv, concat=False, add_self_loops=True) on MI355X.
// R12: ZERO per-edge device atomics. CSR build via bucket(8)xslice(32) blocks:
// LDS-private histogram -> cnt_priv[s][node] (plain stores); scan makes
// per-slice exclusive prefixes; scatter seeds LDS cursors from
// rowptr+cnt_priv and places edges with LDS atomics only. gemm unfused.
// (R11 discovery: 1.6M device atomics ran at ~16G/s = ~100us each for
// hist-in-gemm and cursor-scatter.)
// ---------------------------------------------------------------------------

#define NS 32        // edge slices
#define NB 8         // node buckets (XCD-affine via blockIdx&7)
#define MAXNPB 8192  // max nodes per bucket (N <= 65536)

__device__ __forceinline__ float lrelu(float x) { return x > 0.f ? x : 0.2f * x; }

__device__ __forceinline__ unsigned int fenc(float f) {
    unsigned int u = __float_as_uint(f);
    return (u & 0x80000000u) ? ~u : (u | 0x80000000u);
}
__device__ __forceinline__ float fdec(unsigned int e) {
    unsigned int u = (e & 0x80000000u) ? (e & 0x7FFFFFFFu) : ~e;
    return __uint_as_float(u);
}

__device__ __forceinline__ unsigned short f2bf(float x) {
    unsigned u = __float_as_uint(x);
    return (unsigned short)((u + 0x7FFFu + ((u >> 16) & 1u)) >> 16);
}
__device__ __forceinline__ float bflo(unsigned w) { return __uint_as_float(w << 16); }
__device__ __forceinline__ float bfhi(unsigned w) { return __uint_as_float(w & 0xFFFF0000u); }

__device__ __forceinline__ unsigned pack_h2(float a, float b) {
    const __half2 h = __float22half2_rn(make_float2(a, b));
    return *(const unsigned*)&h;
}
__device__ __forceinline__ float2 unpack_h2(unsigned w) {
    __half2 h = *(const __half2*)&w;
    return __half22float2(h);
}

// ---------------- hist: bucket x slice, LDS-private, no global atomics -----
__global__ __launch_bounds__(256) void hist_kernel(
    const int* __restrict__ dst, int* __restrict__ cnt_priv,
    int E, int n, int npb) {
    __shared__ int h[MAXNPB];
    const int b = blockIdx.x & (NB - 1);
    const int s = blockIdx.x / NB;
    const int lo = b * npb;
    const int hi = min(lo + npb, n);
    const int span = hi - lo;
    if (span <= 0) return;
    for (int j = threadIdx.x; j < span; j += 256) h[j] = 0;
    __syncthreads();
    const int E4 = E >> 2;
    const int len4 = (E4 + NS - 1) / NS;
    const int beg4 = s * len4;
    const int end4 = min(beg4 + len4, E4);
    const int4* dst4 = (const int4*)dst;
    for (int i = beg4 + threadIdx.x; i < end4; i += 256) {
        const int4 d = dst4[i];
        if (d.x >= lo && d.x < hi) atomicAdd(&h[d.x - lo], 1);
        if (d.y >= lo && d.y < hi) atomicAdd(&h[d.y - lo], 1);
        if (d.z >= lo && d.z < hi) atomicAdd(&h[d.z - lo], 1);
        if (d.w >= lo && d.w < hi) atomicAdd(&h[d.w - lo], 1);
    }
    if (s == NS - 1) {
        for (int i = (E4 << 2) + threadIdx.x; i < E; i += 256) {
            const int d = dst[i];
            if (d >= lo && d < hi) atomicAdd(&h[d - lo], 1);
        }
    }
    __syncthreads();
    int* outp = cnt_priv + (size_t)s * n + lo;
    for (int j = threadIdx.x; j < span; j += 256) outp[j] = h[j];
}

// ---------------- scan stage 1: slice prefix (in place) + block sums -------
__global__ __launch_bounds__(256) void scan_part(int* __restrict__ cnt_priv,
                                                 int* __restrict__ deg,
                                                 int* __restrict__ bsum, int n) {
    __shared__ int red[256];
    const int t = threadIdx.x;
    const int node = blockIdx.x * 256 + t;
    int run = 0;
    if (node < n) {
#pragma unroll 4
        for (int s = 0; s < NS; ++s) {
            int* p = &cnt_priv[(size_t)s * n + node];
            const int c = *p;
            *p = run;       // exclusive prefix over slices
            run += c;
        }
        deg[node] = run;
    }
    red[t] = (node < n) ? run : 0;
    __syncthreads();
    for (int o = 128; o > 0; o >>= 1) {
        if (t < o) red[t] += red[t + o];
        __syncthreads();
    }
    if (t == 0) bsum[blockIdx.x] = red[0];
}

__global__ __launch_bounds__(256) void scan_mid(const int* __restrict__ bsum,
                                                int* __restrict__ boff, int nb,
                                                int* __restrict__ rowptr, int n) {
    __shared__ int s[256];
    const int t = threadIdx.x;
    const int v = (t < nb) ? bsum[t] : 0;
    s[t] = v;
    __syncthreads();
    for (int o = 1; o < 256; o <<= 1) {
        const int u = (t >= o) ? s[t - o] : 0;
        __syncthreads();
        s[t] += u;
        __syncthreads();
    }
    if (t < nb) boff[t] = s[t] - v;   // exclusive block offset
    if (t == 255) rowptr[n] = s[255]; // total
}

__global__ __launch_bounds__(256) void scan_final(const int* __restrict__ deg,
                                                  const int* __restrict__ boff,
                                                  int* __restrict__ rowptr, int n) {
    __shared__ int s[256];
    const int t = threadIdx.x;
    const int i = blockIdx.x * 256 + t;
    const int v = (i < n) ? deg[i] : 0;
    s[t] = v;
    __syncthreads();
    for (int o = 1; o < 256; o <<= 1) {
        const int u = (t >= o) ? s[t - o] : 0;
        __syncthreads();
        s[t] += u;
        __syncthreads();
    }
    if (i < n) rowptr[i] = boff[blockIdx.x] + s[t] - v;
}

// ---------------- scatter: LDS cursor seeded from rowptr+cnt_priv ----------
// Record: low32 = src*16, high32 = dst*16 (byte offsets into 16B-row tables).
__global__ __launch_bounds__(256) void scatter_kernel(
    const int* __restrict__ src, const int* __restrict__ dst,
    const int* __restrict__ rowptr, const int* __restrict__ cnt_priv,
    unsigned long long* __restrict__ sd, int E, int n, int npb) {
    __shared__ int cur[MAXNPB];
    const int b = blockIdx.x & (NB - 1);
    const int s = blockIdx.x / NB;
    const int lo = b * npb;
    const int hi = min(lo + npb, n);
    const int span = hi - lo;
    if (span <= 0) return;
    {
        const int* cp = cnt_priv + (size_t)s * n + lo;
        const int* rp = rowptr + lo;
        for (int j = threadIdx.x; j < span; j += 256) cur[j] = rp[j] + cp[j];
    }
    __syncthreads();
    const int E4 = E >> 2;
    const int len4 = (E4 + NS - 1) / NS;
    const int beg4 = s * len4;
    const int end4 = min(beg4 + len4, E4);
    const int4* dst4 = (const int4*)dst;
    const int4* src4 = (const int4*)src;
    for (int i = beg4 + threadIdx.x; i < end4; i += 256) {
        const int4 d = dst4[i];
        const int4 sv = src4[i];
        if (d.x >= lo && d.x < hi) {
            const int p = atomicAdd(&cur[d.x - lo], 1);
            sd[p] = ((unsigned long long)(unsigned)(d.x << 4) << 32) | (unsigned)(sv.x << 4);
        }
        if (d.y >= lo && d.y < hi) {
            const int p = atomicAdd(&cur[d.y - lo], 1);
            sd[p] = ((unsigned long long)(unsigned)(d.y << 4) << 32) | (unsigned)(sv.y << 4);
        }
        if (d.z >= lo && d.z < hi) {
            const int p = atomicAdd(&cur[d.z - lo], 1);
            sd[p] = ((unsigned long long)(unsigned)(d.z << 4) << 32) | (unsigned)(sv.z << 4);
        }
        if (d.w >= lo && d.w < hi) {
            const int p = atomicAdd(&cur[d.w - lo], 1);
            sd[p] = ((unsigned long long)(unsigned)(d.w << 4) << 32) | (unsigned)(sv.w << 4);
        }
    }
    if (s == NS - 1) {
        for (int i = (E4 << 2) + threadIdx.x; i < E; i += 256) {
            const int d = dst[i];
            if (d >= lo && d < hi) {
                const int p = atomicAdd(&cur[d - lo], 1);
                sd[p] = ((unsigned long long)(unsigned)(d << 4) << 32) | (unsigned)(src[i] << 4);
            }
        }
    }
}

// ---------------- per-edge softmax weights (fp16 pairs, u64 record) --------
__global__ __launch_bounds__(256) void edge_w_kernel(
    const unsigned long long* __restrict__ sd,
    const float* __restrict__ asrc, const float* __restrict__ adst,
    const unsigned int* __restrict__ gmax, unsigned long long* __restrict__ wq,
    int Etot) {
    const char* aB = (const char*)asrc;
    const char* dB = (const char*)adst;
    const float g0 = fdec(gmax[0]), g1 = fdec(gmax[1]);
    const float g2 = fdec(gmax[2]), g3 = fdec(gmax[3]);
    for (int i = blockIdx.x * blockDim.x + threadIdx.x; i < Etot;
         i += gridDim.x * blockDim.x) {
        const unsigned long long rec = __builtin_nontemporal_load(&sd[i]);
        const unsigned s16 = (unsigned)rec;
        const unsigned d16 = (unsigned)(rec >> 32);
        const float4 as = *(const float4*)(aB + s16);
        const float4 ad = *(const float4*)(dB + d16);
        const float q0 = __expf(lrelu(as.x + ad.x) - lrelu(g0 + ad.x));
        const float q1 = __expf(lrelu(as.y + ad.y) - lrelu(g1 + ad.y));
        const float q2 = __expf(lrelu(as.z + ad.z) - lrelu(g2 + ad.z));
        const float q3 = __expf(lrelu(as.w + ad.w) - lrelu(g3 + ad.w));
        const unsigned lo = pack_h2(q0, q1);
        const unsigned hi = pack_h2(q2, q3);
        const unsigned long long out = ((unsigned long long)hi << 32) | lo;
        __builtin_nontemporal_store(out, &wq[i]);
    }
}

// ---------------- GEMM + alpha + global head max (pure, no hist) -----------
// 64 rows/block, acc[8][4]; k unrolled x4.
// Hb layout (bf16): dword f of half (head&1) = [low: head hp, high: hp+2].
template <int K>
__global__ __launch_bounds__(256) void gemm_kernel(
    const float* __restrict__ X, const float* __restrict__ W,
    const float* __restrict__ AttS, const float* __restrict__ AttD,
    unsigned short* __restrict__ Hb, float* __restrict__ asrc, float* __restrict__ adst,
    unsigned int* __restrict__ gmax, int n) {
    constexpr int KC = 32;
    __shared__ __align__(16) float Ws[KC * 128];
    __shared__ __align__(16) float Xs[64 * K];
    __shared__ unsigned int smax[4];
    const int tid = threadIdx.x;

    const int r = tid >> 5;          // row-in-batch 0..7
    const int sub = tid & 31;
    const int head = sub >> 3;       // 0..3
    const int pos = ((head & 1) << 1) | (head >> 1);  // [0,2,1,3] order
    const int fc = (sub & 7) * 4;    // feat-in-head base
    const int rowBase = blockIdx.x * 64;

    if (tid < 4) smax[tid] = 0u;
    {
        const float4* X4 = (const float4*)X;
        float4* Xs4 = (float4*)Xs;
        const int K4 = K / 4;
        for (int i = tid; i < 64 * K4; i += 256) {
            int rr = rowBase + i / K4;
            Xs4[i] = (rr < n) ? X4[(size_t)rr * K4 + (i % K4)] : make_float4(0.f, 0.f, 0.f, 0.f);
        }
    }

    float acc[8][4] = {};
    const float4* Ws4 = (const float4*)Ws;
    for (int kt = 0; kt < K; kt += KC) {
        __syncthreads();
        {
            const float4* W4 = (const float4*)(W + kt * 128);
            float4* WsS = (float4*)Ws;
#pragma unroll
            for (int i = 0; i < 4; ++i) WsS[tid + i * 256] = W4[tid + i * 256];
        }
        __syncthreads();
#pragma unroll
        for (int k = 0; k < KC; k += 4) {
            float4 wv[4];
#pragma unroll
            for (int j = 0; j < 4; ++j) wv[j] = Ws4[(k + j) * 32 + sub];
            float4 xv[8];
#pragma unroll
            for (int b = 0; b < 8; ++b)
                xv[b] = *(const float4*)&Xs[(b * 8 + r) * K + kt + k];
#pragma unroll
            for (int b = 0; b < 8; ++b) {
                acc[b][0] = fmaf(xv[b].x, wv[0].x, acc[b][0]);
                acc[b][1] = fmaf(xv[b].x, wv[0].y, acc[b][1]);
                acc[b][2] = fmaf(xv[b].x, wv[0].z, acc[b][2]);
                acc[b][3] = fmaf(xv[b].x, wv[0].w, acc[b][3]);
                acc[b][0] = fmaf(xv[b].y, wv[1].x, acc[b][0]);
                acc[b][1] = fmaf(xv[b].y, wv[1].y, acc[b][1]);
                acc[b][2] = fmaf(xv[b].y, wv[1].z, acc[b][2]);
                acc[b][3] = fmaf(xv[b].y, wv[1].w, acc[b][3]);
                acc[b][0] = fmaf(xv[b].z, wv[2].x, acc[b][0]);
                acc[b][1] = fmaf(xv[b].z, wv[2].y, acc[b][1]);
                acc[b][2] = fmaf(xv[b].z, wv[2].z, acc[b][2]);
                acc[b][3] = fmaf(xv[b].z, wv[2].w, acc[b][3]);
                acc[b][0] = fmaf(xv[b].w, wv[3].x, acc[b][0]);
                acc[b][1] = fmaf(xv[b].w, wv[3].y, acc[b][1]);
                acc[b][2] = fmaf(xv[b].w, wv[3].z, acc[b][2]);
                acc[b][3] = fmaf(xv[b].w, wv[3].w, acc[b][3]);
            }
        }
    }

    float a_s[4], a_d[4];
#pragma unroll
    for (int j = 0; j < 4; ++j) {
        a_s[j] = AttS[head * 32 + fc + j];
        a_d[j] = AttD[head * 32 + fc + j];
    }
#pragma unroll
    for (int b = 0; b < 8; ++b) {
        const int row = rowBase + b * 8 + r;
        const float p0 = __shfl_xor(acc[b][0], 16);
        const float p1 = __shfl_xor(acc[b][1], 16);
        const float p2 = __shfl_xor(acc[b][2], 16);
        const float p3 = __shfl_xor(acc[b][3], 16);
        if (row < n) {
            if (head < 2) {
                uint4 o;
                o.x = (unsigned)f2bf(acc[b][0]) | ((unsigned)f2bf(p0) << 16);
                o.y = (unsigned)f2bf(acc[b][1]) | ((unsigned)f2bf(p1) << 16);
                o.z = (unsigned)f2bf(acc[b][2]) | ((unsigned)f2bf(p2) << 16);
                o.w = (unsigned)f2bf(acc[b][3]) | ((unsigned)f2bf(p3) << 16);
                *(uint4*)((char*)Hb + (size_t)row * 256 + head * 128 + fc * 4) = o;
            }
            float ps = acc[b][0] * a_s[0] + acc[b][1] * a_s[1] +
                       acc[b][2] * a_s[2] + acc[b][3] * a_s[3];
            float pd = acc[b][0] * a_d[0] + acc[b][1] * a_d[1] +
                       acc[b][2] * a_d[2] + acc[b][3] * a_d[3];
#pragma unroll
            for (int msk = 1; msk < 8; msk <<= 1) {
                ps += __shfl_xor(ps, msk);
                pd += __shfl_xor(pd, msk);
            }
            if ((sub & 7) == 0) {
                asrc[row * 4 + pos] = ps;
                adst[row * 4 + pos] = pd;
                atomicMax(&smax[pos], fenc(ps));
            }
        }
    }
    __syncthreads();
    if (tid < 4) atomicMax(&gmax[tid], smax[tid]);
}

// ---------------- per-node aggregate (weights precomputed) ----------------
__global__ __launch_bounds__(256) void node_kernel(
    const int* __restrict__ rowptr, const unsigned long long* __restrict__ sd,
    const unsigned short* __restrict__ Hb, const float* __restrict__ asrc,
    const float* __restrict__ adst, const unsigned int* __restrict__ gmax,
    const unsigned long long* __restrict__ wq, const float* __restrict__ bias,
    float* __restrict__ outp, int n, int apply_elu) {
    const int node = blockIdx.x * 4 + (threadIdx.x >> 6);
    if (node >= n) return;
    const int lane = threadIdx.x & 63;
    const unsigned f = lane & 31;
    const unsigned hp = lane >> 5;            // 0/1
    const unsigned hp8 = hp * 8;              // byte off into asrc/adst row (16B)
    const unsigned hp4 = hp * 4;              // byte off into wq record (8B)
    const unsigned hpf = hp * 128 + f * 4;    // byte off into Hb row (256B)
    const unsigned node16 = (unsigned)node * 16;
    const char* aB = (const char*)asrc;
    const char* dB = (const char*)adst;
    const char* hB = (const char*)Hb;
    const char* wB = (const char*)wq;

    const int beg = rowptr[node], end = rowptr[node + 1];
    const float2 ad01 = *(const float2*)(dB + node16 + hp8);
    const float2 M01 = make_float2(lrelu(fdec(gmax[hp * 2]) + ad01.x),
                                   lrelu(fdec(gmax[hp * 2 + 1]) + ad01.y));

    const float2 aself = *(const float2*)(aB + node16 + hp8);
    float2 q = make_float2(__expf(lrelu(aself.x + ad01.x) - M01.x),
                           __expf(lrelu(aself.y + ad01.y) - M01.y));
    float2 s01 = q;
    const unsigned wSelf = *(const unsigned*)(hB + (node16 << 4) + hpf);
    float2 acc01 = make_float2(q.x * bflo(wSelf), q.y * bfhi(wSelf));

    int i = beg;
    for (; i + 16 <= end; i += 16) {
        unsigned sx[16];
#pragma unroll
        for (int u = 0; u < 16; ++u)
            sx[u] = (unsigned)__builtin_nontemporal_load(&sd[i + u]);  // low32 = s*16
        unsigned wv[16];
#pragma unroll
        for (int u = 0; u < 16; ++u)
            wv[u] = *(const unsigned*)(wB + (((unsigned)(i + u)) << 3) + hp4);
        unsigned w[16];
#pragma unroll
        for (int u = 0; u < 16; ++u) w[u] = *(const unsigned*)(hB + (sx[u] << 4) + hpf);
#pragma unroll
        for (int u = 0; u < 16; ++u) {
            const float2 qf = unpack_h2(wv[u]);
            s01.x += qf.x; s01.y += qf.y;
            acc01.x = fmaf(qf.x, bflo(w[u]), acc01.x);
            acc01.y = fmaf(qf.y, bfhi(w[u]), acc01.y);
        }
    }
    for (; i + 4 <= end; i += 4) {
        unsigned sx[4];
#pragma unroll
        for (int u = 0; u < 4; ++u)
            sx[u] = (unsigned)__builtin_nontemporal_load(&sd[i + u]);
        unsigned wv[4];
#pragma unroll
        for (int u = 0; u < 4; ++u)
            wv[u] = *(const unsigned*)(wB + (((unsigned)(i + u)) << 3) + hp4);
        unsigned w[4];
#pragma unroll
        for (int u = 0; u < 4; ++u) w[u] = *(const unsigned*)(hB + (sx[u] << 4) + hpf);
#pragma unroll
        for (int u = 0; u < 4; ++u) {
            const float2 qf = unpack_h2(wv[u]);
            s01.x += qf.x; s01.y += qf.y;
            acc01.x = fmaf(qf.x, bflo(w[u]), acc01.x);
            acc01.y = fmaf(qf.y, bfhi(w[u]), acc01.y);
        }
    }
    for (; i < end; ++i) {
        const unsigned sx = (unsigned)__builtin_nontemporal_load(&sd[i]);
        const unsigned wh = *(const unsigned*)(wB + (((unsigned)i) << 3) + hp4);
        const unsigned wv = *(const unsigned*)(hB + (sx << 4) + hpf);
        const float2 qf = unpack_h2(wh);
        s01.x += qf.x; s01.y += qf.y;
        acc01.x = fmaf(qf.x, bflo(wv), acc01.x);
        acc01.y = fmaf(qf.y, bfhi(wv), acc01.y);
    }

    float v = acc01.x / s01.x + acc01.y / s01.y;
    v += __shfl_xor(v, 32);     // add the other head pair
    v = v * 0.25f + bias[f];
    if (apply_elu) v = (v > 0.f) ? v : (__expf(v) - 1.f);
    if (lane < 32) outp[(size_t)node * 32 + f] = v;
}

// ---------------- launch ----------------

extern "C" void kernel_launch(void* const* d_in, const int* in_sizes, int n_in,
                              void* d_out, int out_size, void* d_ws, size_t ws_size,
                              hipStream_t stream) {
    const int N = in_sizes[0] / 128;
    const int E = in_sizes[1] / 2;
    const float* x = (const float*)d_in[0];
    const int* ei = (const int*)d_in[1];
    const float* W1 = (const float*)d_in[2];
    const float* atS1 = (const float*)d_in[3];
    const float* atD1 = (const float*)d_in[4];
    const float* b1 = (const float*)d_in[5];
    const float* W2 = (const float*)d_in[6];
    const float* atS2 = (const float*)d_in[7];
    const float* atD2 = (const float*)d_in[8];
    const float* b2 = (const float*)d_in[9];
    float* out = (float*)d_out;

    char* ws = (char*)d_ws;
    size_t off = 0;
    auto alloc = [&](size_t bytes) {
        void* p = ws + off;
        off = (off + bytes + 255) & ~(size_t)255;
        return p;
    };
    unsigned int* gmax = (unsigned int*)alloc(8 * sizeof(unsigned int)); // [layer][pos]
    int* cnt_priv = (int*)alloc((size_t)NS * N * 4);  // per-slice counts -> prefixes
    int* deg = (int*)alloc((size_t)N * 4);
    int* rowptr = (int*)alloc((size_t)(N + 1) * 4);
    int* bsum = (int*)alloc(256 * 4);
    int* boff = (int*)alloc(256 * 4);
    unsigned long long* sd = (unsigned long long*)alloc((size_t)E * 8);
    unsigned long long* wq = (unsigned long long*)alloc((size_t)E * 8);
    unsigned short* hb = (unsigned short*)alloc((size_t)N * 128 * 2);  // packed bf16
    float* av_s = (float*)alloc((size_t)N * 4 * 4);
    float* av_d = (float*)alloc((size_t)N * 4 * 4);
    float* x2 = (float*)alloc((size_t)N * 32 * 4);

    const int* e_src = ei;
    const int* e_dst = ei + E;

    const int gemmGrid = (N + 63) / 64;
    const int nodeGrid = (N + 3) / 4;
    const int npb = (N + NB - 1) / NB;       // nodes per bucket (<= MAXNPB)
    const int scanGrid = (N + 255) / 256;    // must be <= 256
    const int bsGrid = NB * NS;              // bucket x slice blocks

    (void)hipMemsetAsync(gmax, 0, 8 * sizeof(unsigned int), stream);

    // CSR build (no device atomics)
    hist_kernel<<<bsGrid, 256, 0, stream>>>(e_dst, cnt_priv, E, N, npb);
    scan_part<<<scanGrid, 256, 0, stream>>>(cnt_priv, deg, bsum, N);
    scan_mid<<<1, 256, 0, stream>>>(bsum, boff, scanGrid, rowptr, N);
    scan_final<<<scanGrid, 256, 0, stream>>>(deg, boff, rowptr, N);
    scatter_kernel<<<bsGrid, 256, 0, stream>>>(e_src, e_dst, rowptr, cnt_priv, sd, E, N, npb);

    // layer 1
    gemm_kernel<128><<<gemmGrid, 256, 0, stream>>>(
        x, W1, atS1, atD1, hb, av_s, av_d, gmax, N);
    edge_w_kernel<<<2048, 256, 0, stream>>>(sd, av_s, av_d, gmax, wq, E);
    node_kernel<<<nodeGrid, 256, 0, stream>>>(rowptr, sd, hb, av_s, av_d, gmax,
                                              wq, b1, x2, N, 1);
    // layer 2
    gemm_kernel<32><<<gemmGrid, 256, 0, stream>>>(
        x2, W2, atS2, atD2, hb, av_s, av_d, gmax + 4, N);
    edge_w_kernel<<<2048, 256, 0, stream>>>(sd, av_s, av_d, gmax + 4, wq, E);
    node_kernel<<<nodeGrid, 256, 0, stream>>>(rowptr, sd, hb, av_s, av_d, gmax + 4,
                                              wq, b2, out, N, 0);
}

// Round 13
// 365.427 us; speedup vs baseline: 1.1905x; 1.0212x over previous
//
#include <hip/hip_runtime.h>
#include <hip/hip_bf16.h>
#include <hip/hip_fp16.h>
#include <math.h>

// ---------------------------------------------------------------------------
// 2-layer GAT (PyG GATConv, concat=False, add_self_loops=True) on MI355X.
// R13: 32-lane-per-node aggregate (all 4 heads in-lane via [row][f][hp] u64
// Hb layout, 2 nodes/wave), unified 16B edge record {src16,dst16,q01,q23}
// (layer-1 q fused into scatter, layer-2 edge_w rewrites q in place),
// NS=64 CSR-build slices. Zero per-edge device atomics (R12).
// ---------------------------------------------------------------------------

#define NS 64        // edge slices
#define NB 8         // node buckets (XCD-affine via blockIdx&7)
#define MAXNPB 8192  // max nodes per bucket (N <= 65536)

__device__ __forceinline__ float lrelu(float x) { return x > 0.f ? x : 0.2f * x; }

__device__ __forceinline__ unsigned int fenc(float f) {
    unsigned int u = __float_as_uint(f);
    return (u & 0x80000000u) ? ~u : (u | 0x80000000u);
}
__device__ __forceinline__ float fdec(unsigned int e) {
    unsigned int u = (e & 0x80000000u) ? (e & 0x7FFFFFFFu) : ~e;
    return __uint_as_float(u);
}

__device__ __forceinline__ unsigned short f2bf(float x) {
    unsigned u = __float_as_uint(x);
    return (unsigned short)((u + 0x7FFFu + ((u >> 16) & 1u)) >> 16);
}
__device__ __forceinline__ float bflo(unsigned w) { return __uint_as_float(w << 16); }
__device__ __forceinline__ float bfhi(unsigned w) { return __uint_as_float(w & 0xFFFF0000u); }

__device__ __forceinline__ unsigned pack_h2(float a, float b) {
    const __half2 h = __float22half2_rn(make_float2(a, b));
    return *(const unsigned*)&h;
}
__device__ __forceinline__ float2 unpack_h2(unsigned w) {
    __half2 h = *(const __half2*)&w;
    return __half22float2(h);
}

// ---------------- hist: bucket x slice, LDS-private, no global atomics -----
__global__ __launch_bounds__(256) void hist_kernel(
    const int* __restrict__ dst, int* __restrict__ cnt_priv,
    int E, int n, int npb) {
    __shared__ int h[MAXNPB];
    const int b = blockIdx.x & (NB - 1);
    const int s = blockIdx.x / NB;
    const int lo = b * npb;
    const int hi = min(lo + npb, n);
    const int span = hi - lo;
    if (span <= 0) return;
    for (int j = threadIdx.x; j < span; j += 256) h[j] = 0;
    __syncthreads();
    const int E4 = E >> 2;
    const int len4 = (E4 + NS - 1) / NS;
    const int beg4 = s * len4;
    const int end4 = min(beg4 + len4, E4);
    const int4* dst4 = (const int4*)dst;
    for (int i = beg4 + threadIdx.x; i < end4; i += 256) {
        const int4 d = dst4[i];
        if (d.x >= lo && d.x < hi) atomicAdd(&h[d.x - lo], 1);
        if (d.y >= lo && d.y < hi) atomicAdd(&h[d.y - lo], 1);
        if (d.z >= lo && d.z < hi) atomicAdd(&h[d.z - lo], 1);
        if (d.w >= lo && d.w < hi) atomicAdd(&h[d.w - lo], 1);
    }
    if (s == NS - 1) {
        for (int i = (E4 << 2) + threadIdx.x; i < E; i += 256) {
            const int d = dst[i];
            if (d >= lo && d < hi) atomicAdd(&h[d - lo], 1);
        }
    }
    __syncthreads();
    int* outp = cnt_priv + (size_t)s * n + lo;
    for (int j = threadIdx.x; j < span; j += 256) outp[j] = h[j];
}

// ---------------- scan stage 1: slice prefix (in place) + block sums -------
__global__ __launch_bounds__(256) void scan_part(int* __restrict__ cnt_priv,
                                                 int* __restrict__ deg,
                                                 int* __restrict__ bsum, int n) {
    __shared__ int red[256];
    const int t = threadIdx.x;
    const int node = blockIdx.x * 256 + t;
    int run = 0;
    if (node < n) {
#pragma unroll 4
        for (int s = 0; s < NS; ++s) {
            int* p = &cnt_priv[(size_t)s * n + node];
            const int c = *p;
            *p = run;       // exclusive prefix over slices
            run += c;
        }
        deg[node] = run;
    }
    red[t] = (node < n) ? run : 0;
    __syncthreads();
    for (int o = 128; o > 0; o >>= 1) {
        if (t < o) red[t] += red[t + o];
        __syncthreads();
    }
    if (t == 0) bsum[blockIdx.x] = red[0];
}

__global__ __launch_bounds__(256) void scan_mid(const int* __restrict__ bsum,
                                                int* __restrict__ boff, int nb,
                                                int* __restrict__ rowptr, int n) {
    __shared__ int s[256];
    const int t = threadIdx.x;
    const int v = (t < nb) ? bsum[t] : 0;
    s[t] = v;
    __syncthreads();
    for (int o = 1; o < 256; o <<= 1) {
        const int u = (t >= o) ? s[t - o] : 0;
        __syncthreads();
        s[t] += u;
        __syncthreads();
    }
    if (t < nb) boff[t] = s[t] - v;   // exclusive block offset
    if (t == 255) rowptr[n] = s[255]; // total
}

__global__ __launch_bounds__(256) void scan_final(const int* __restrict__ deg,
                                                  const int* __restrict__ boff,
                                                  int* __restrict__ rowptr, int n) {
    __shared__ int s[256];
    const int t = threadIdx.x;
    const int i = blockIdx.x * 256 + t;
    const int v = (i < n) ? deg[i] : 0;
    s[t] = v;
    __syncthreads();
    for (int o = 1; o < 256; o <<= 1) {
        const int u = (t >= o) ? s[t - o] : 0;
        __syncthreads();
        s[t] += u;
        __syncthreads();
    }
    if (i < n) rowptr[i] = boff[blockIdx.x] + s[t] - v;
}

// ---------------- scatter + layer-1 edge weights (fused) -------------------
// LDS cursor seeded from rowptr+cnt_priv (no device atomics). Record:
// esd[p] = { src*16, dst*16, half2(q_pos0,q_pos1), half2(q_pos2,q_pos3) }.
__global__ __launch_bounds__(256) void scatter_kernel(
    const int* __restrict__ src, const int* __restrict__ dst,
    const int* __restrict__ rowptr, const int* __restrict__ cnt_priv,
    const float* __restrict__ asrc, const float* __restrict__ adst,
    const unsigned int* __restrict__ gmax,
    uint4* __restrict__ esd, int E, int n, int npb) {
    __shared__ int cur[MAXNPB];
    const int b = blockIdx.x & (NB - 1);
    const int s = blockIdx.x / NB;
    const int lo = b * npb;
    const int hi = min(lo + npb, n);
    const int span = hi - lo;
    if (span <= 0) return;
    {
        const int* cp = cnt_priv + (size_t)s * n + lo;
        const int* rp = rowptr + lo;
        for (int j = threadIdx.x; j < span; j += 256) cur[j] = rp[j] + cp[j];
    }
    __syncthreads();
    const char* aB = (const char*)asrc;
    const char* dB = (const char*)adst;
    const float g0 = fdec(gmax[0]), g1 = fdec(gmax[1]);
    const float g2 = fdec(gmax[2]), g3 = fdec(gmax[3]);

    auto place = [&](int sv, int dv) {
        const int p = atomicAdd(&cur[dv - lo], 1);
        const unsigned s16 = (unsigned)(sv << 4);
        const unsigned d16 = (unsigned)(dv << 4);
        const float4 as = *(const float4*)(aB + s16);
        const float4 ad = *(const float4*)(dB + d16);
        const float q0 = __expf(lrelu(as.x + ad.x) - lrelu(g0 + ad.x));
        const float q1 = __expf(lrelu(as.y + ad.y) - lrelu(g1 + ad.y));
        const float q2 = __expf(lrelu(as.z + ad.z) - lrelu(g2 + ad.z));
        const float q3 = __expf(lrelu(as.w + ad.w) - lrelu(g3 + ad.w));
        esd[p] = make_uint4(s16, d16, pack_h2(q0, q1), pack_h2(q2, q3));
    };

    const int E4 = E >> 2;
    const int len4 = (E4 + NS - 1) / NS;
    const int beg4 = s * len4;
    const int end4 = min(beg4 + len4, E4);
    const int4* dst4 = (const int4*)dst;
    const int4* src4 = (const int4*)src;
    for (int i = beg4 + threadIdx.x; i < end4; i += 256) {
        const int4 d = dst4[i];
        const int4 sv = src4[i];
        if (d.x >= lo && d.x < hi) place(sv.x, d.x);
        if (d.y >= lo && d.y < hi) place(sv.y, d.y);
        if (d.z >= lo && d.z < hi) place(sv.z, d.z);
        if (d.w >= lo && d.w < hi) place(sv.w, d.w);
    }
    if (s == NS - 1) {
        for (int i = (E4 << 2) + threadIdx.x; i < E; i += 256) {
            const int d = dst[i];
            if (d >= lo && d < hi) place(src[i], d);
        }
    }
}

// ---------------- layer-2 edge weights (rewrite q half of esd) -------------
__global__ __launch_bounds__(256) void edge_w_kernel(
    uint4* __restrict__ esd,
    const float* __restrict__ asrc, const float* __restrict__ adst,
    const unsigned int* __restrict__ gmax, int Etot) {
    const char* aB = (const char*)asrc;
    const char* dB = (const char*)adst;
    const float g0 = fdec(gmax[0]), g1 = fdec(gmax[1]);
    const float g2 = fdec(gmax[2]), g3 = fdec(gmax[3]);
    for (int i = blockIdx.x * blockDim.x + threadIdx.x; i < Etot;
         i += gridDim.x * blockDim.x) {
        const unsigned long long sd =
            __builtin_nontemporal_load((const unsigned long long*)&esd[i]);
        const unsigned s16 = (unsigned)sd;
        const unsigned d16 = (unsigned)(sd >> 32);
        const float4 as = *(const float4*)(aB + s16);
        const float4 ad = *(const float4*)(dB + d16);
        const float q0 = __expf(lrelu(as.x + ad.x) - lrelu(g0 + ad.x));
        const float q1 = __expf(lrelu(as.y + ad.y) - lrelu(g1 + ad.y));
        const float q2 = __expf(lrelu(as.z + ad.z) - lrelu(g2 + ad.z));
        const float q3 = __expf(lrelu(as.w + ad.w) - lrelu(g3 + ad.w));
        const unsigned long long rec =
            ((unsigned long long)pack_h2(q2, q3) << 32) | pack_h2(q0, q1);
        __builtin_nontemporal_store(
            rec, (unsigned long long*)((char*)&esd[i] + 8));
    }
}

// ---------------- GEMM + alpha + global head max ---------------------------
// 64 rows/block, acc[8][4]; k unrolled x4.
// Hb layout (bf16): row*256 + f*8 + hp*4 -> dword = (head hp | head hp+2<<16).
template <int K>
__global__ __launch_bounds__(256) void gemm_kernel(
    const float* __restrict__ X, const float* __restrict__ W,
    const float* __restrict__ AttS, const float* __restrict__ AttD,
    unsigned short* __restrict__ Hb, float* __restrict__ asrc, float* __restrict__ adst,
    unsigned int* __restrict__ gmax, int n) {
    constexpr int KC = 32;
    __shared__ __align__(16) float Ws[KC * 128];
    __shared__ __align__(16) float Xs[64 * K];
    __shared__ unsigned int smax[4];
    const int tid = threadIdx.x;

    const int r = tid >> 5;          // row-in-batch 0..7
    const int sub = tid & 31;
    const int head = sub >> 3;       // 0..3
    const int pos = ((head & 1) << 1) | (head >> 1);  // [0,2,1,3] order
    const int fc = (sub & 7) * 4;    // feat-in-head base
    const int rowBase = blockIdx.x * 64;

    if (tid < 4) smax[tid] = 0u;
    {
        const float4* X4 = (const float4*)X;
        float4* Xs4 = (float4*)Xs;
        const int K4 = K / 4;
        for (int i = tid; i < 64 * K4; i += 256) {
            int rr = rowBase + i / K4;
            Xs4[i] = (rr < n) ? X4[(size_t)rr * K4 + (i % K4)] : make_float4(0.f, 0.f, 0.f, 0.f);
        }
    }

    float acc[8][4] = {};
    const float4* Ws4 = (const float4*)Ws;
    for (int kt = 0; kt < K; kt += KC) {
        __syncthreads();
        {
            const float4* W4 = (const float4*)(W + kt * 128);
            float4* WsS = (float4*)Ws;
#pragma unroll
            for (int i = 0; i < 4; ++i) WsS[tid + i * 256] = W4[tid + i * 256];
        }
        __syncthreads();
#pragma unroll
        for (int k = 0; k < KC; k += 4) {
            float4 wv[4];
#pragma unroll
            for (int j = 0; j < 4; ++j) wv[j] = Ws4[(k + j) * 32 + sub];
            float4 xv[8];
#pragma unroll
            for (int b = 0; b < 8; ++b)
                xv[b] = *(const float4*)&Xs[(b * 8 + r) * K + kt + k];
#pragma unroll
            for (int b = 0; b < 8; ++b) {
                acc[b][0] = fmaf(xv[b].x, wv[0].x, acc[b][0]);
                acc[b][1] = fmaf(xv[b].x, wv[0].y, acc[b][1]);
                acc[b][2] = fmaf(xv[b].x, wv[0].z, acc[b][2]);
                acc[b][3] = fmaf(xv[b].x, wv[0].w, acc[b][3]);
                acc[b][0] = fmaf(xv[b].y, wv[1].x, acc[b][0]);
                acc[b][1] = fmaf(xv[b].y, wv[1].y, acc[b][1]);
                acc[b][2] = fmaf(xv[b].y, wv[1].z, acc[b][2]);
                acc[b][3] = fmaf(xv[b].y, wv[1].w, acc[b][3]);
                acc[b][0] = fmaf(xv[b].z, wv[2].x, acc[b][0]);
                acc[b][1] = fmaf(xv[b].z, wv[2].y, acc[b][1]);
                acc[b][2] = fmaf(xv[b].z, wv[2].z, acc[b][2]);
                acc[b][3] = fmaf(xv[b].z, wv[2].w, acc[b][3]);
                acc[b][0] = fmaf(xv[b].w, wv[3].x, acc[b][0]);
                acc[b][1] = fmaf(xv[b].w, wv[3].y, acc[b][1]);
                acc[b][2] = fmaf(xv[b].w, wv[3].z, acc[b][2]);
                acc[b][3] = fmaf(xv[b].w, wv[3].w, acc[b][3]);
            }
        }
    }

    float a_s[4], a_d[4];
#pragma unroll
    for (int j = 0; j < 4; ++j) {
        a_s[j] = AttS[head * 32 + fc + j];
        a_d[j] = AttD[head * 32 + fc + j];
    }
#pragma unroll
    for (int b = 0; b < 8; ++b) {
        const int row = rowBase + b * 8 + r;
        const float p0 = __shfl_xor(acc[b][0], 16);  // partner head^2, same feats
        const float p1 = __shfl_xor(acc[b][1], 16);
        const float p2 = __shfl_xor(acc[b][2], 16);
        const float p3 = __shfl_xor(acc[b][3], 16);
        if (row < n) {
            if (head < 2) {
                char* base = (char*)Hb + (size_t)row * 256 + (unsigned)fc * 8 + head * 4;
                *(unsigned*)(base + 0)  = (unsigned)f2bf(acc[b][0]) | ((unsigned)f2bf(p0) << 16);
                *(unsigned*)(base + 8)  = (unsigned)f2bf(acc[b][1]) | ((unsigned)f2bf(p1) << 16);
                *(unsigned*)(base + 16) = (unsigned)f2bf(acc[b][2]) | ((unsigned)f2bf(p2) << 16);
                *(unsigned*)(base + 24) = (unsigned)f2bf(acc[b][3]) | ((unsigned)f2bf(p3) << 16);
            }
            float ps = acc[b][0] * a_s[0] + acc[b][1] * a_s[1] +
                       acc[b][2] * a_s[2] + acc[b][3] * a_s[3];
            float pd = acc[b][0] * a_d[0] + acc[b][1] * a_d[1] +
                       acc[b][2] * a_d[2] + acc[b][3] * a_d[3];
#pragma unroll
            for (int msk = 1; msk < 8; msk <<= 1) {
                ps += __shfl_xor(ps, msk);
                pd += __shfl_xor(pd, msk);
            }
            if ((sub & 7) == 0) {
                asrc[row * 4 + pos] = ps;
                adst[row * 4 + pos] = pd;
                atomicMax(&smax[pos], fenc(ps));
            }
        }
    }
    __syncthreads();
    if (tid < 4) atomicMax(&gmax[tid], smax[tid]);
}

// ---------------- per-node aggregate: 32 lanes/node, 4 heads in-lane -------
// Lane f loads ONE u64 per edge = all 4 head values for its feature.
// Per edge: 2 nt u64 stream loads (record) + 1 u64 gather, 4 fma.
__global__ __launch_bounds__(256) void node_kernel(
    const int* __restrict__ rowptr, const uint4* __restrict__ esd,
    const unsigned short* __restrict__ Hb, const float* __restrict__ asrc,
    const float* __restrict__ adst, const unsigned int* __restrict__ gmax,
    const float* __restrict__ bias,
    float* __restrict__ outp, int n, int apply_elu) {
    const int node = blockIdx.x * 8 + (threadIdx.x >> 5);
    if (node >= n) return;
    const unsigned f = threadIdx.x & 31;
    const unsigned f8 = f * 8;
    const char* hB = (const char*)Hb;
    const unsigned long long* eB = (const unsigned long long*)esd;

    const int beg = rowptr[node], end = rowptr[node + 1];
    const float4 ad4 = *(const float4*)(adst + (size_t)node * 4);  // pos order
    const float4 as4 = *(const float4*)(asrc + (size_t)node * 4);
    const float M0 = lrelu(fdec(gmax[0]) + ad4.x);
    const float M1 = lrelu(fdec(gmax[1]) + ad4.y);
    const float M2 = lrelu(fdec(gmax[2]) + ad4.z);
    const float M3 = lrelu(fdec(gmax[3]) + ad4.w);

    // self loop
    const float q0 = __expf(lrelu(as4.x + ad4.x) - M0);
    const float q1 = __expf(lrelu(as4.y + ad4.y) - M1);
    const float q2 = __expf(lrelu(as4.z + ad4.z) - M2);
    const float q3 = __expf(lrelu(as4.w + ad4.w) - M3);
    float s0 = q0, s1 = q1, s2 = q2, s3 = q3;
    const uint2 hs = *(const uint2*)(hB + ((size_t)node << 8) + f8);
    float a0 = q0 * bflo(hs.x);   // pos0 = head0
    float a1 = q1 * bfhi(hs.x);   // pos1 = head2
    float a2 = q2 * bflo(hs.y);   // pos2 = head1
    float a3 = q3 * bfhi(hs.y);   // pos3 = head3

    int i = beg;
    for (; i + 8 <= end; i += 8) {
        unsigned long long e0[8], e1[8];
#pragma unroll
        for (int u = 0; u < 8; ++u) {
            e0[u] = __builtin_nontemporal_load(&eB[(size_t)(i + u) * 2]);      // {s16,d16}
            e1[u] = __builtin_nontemporal_load(&eB[(size_t)(i + u) * 2 + 1]);  // {q01,q23}
        }
        uint2 h[8];
#pragma unroll
        for (int u = 0; u < 8; ++u)
            h[u] = *(const uint2*)(hB + (((unsigned)e0[u]) << 4) + f8);
#pragma unroll
        for (int u = 0; u < 8; ++u) {
            const float2 qa = unpack_h2((unsigned)e1[u]);
            const float2 qb = unpack_h2((unsigned)(e1[u] >> 32));
            s0 += qa.x; s1 += qa.y; s2 += qb.x; s3 += qb.y;
            a0 = fmaf(qa.x, bflo(h[u].x), a0);
            a1 = fmaf(qa.y, bfhi(h[u].x), a1);
            a2 = fmaf(qb.x, bflo(h[u].y), a2);
            a3 = fmaf(qb.y, bfhi(h[u].y), a3);
        }
    }
    for (; i < end; ++i) {
        const unsigned long long e0 = __builtin_nontemporal_load(&eB[(size_t)i * 2]);
        const unsigned long long e1 = __builtin_nontemporal_load(&eB[(size_t)i * 2 + 1]);
        const uint2 h = *(const uint2*)(hB + (((unsigned)e0) << 4) + f8);
        const float2 qa = unpack_h2((unsigned)e1);
        const float2 qb = unpack_h2((unsigned)(e1 >> 32));
        s0 += qa.x; s1 += qa.y; s2 += qb.x; s3 += qb.y;
        a0 = fmaf(qa.x, bflo(h.x), a0);
        a1 = fmaf(qa.y, bfhi(h.x), a1);
        a2 = fmaf(qb.x, bflo(h.y), a2);
        a3 = fmaf(qb.y, bfhi(h.y), a3);
    }

    float v = a0 / s0 + a1 / s1 + a2 / s2 + a3 / s3;
    v = v * 0.25f + bias[f];
    if (apply_elu) v = (v > 0.f) ? v : (__expf(v) - 1.f);
    outp[(size_t)node * 32 + f] = v;
}

// ---------------- launch ----------------

extern "C" void kernel_launch(void* const* d_in, const int* in_sizes, int n_in,
                              void* d_out, int out_size, void* d_ws, size_t ws_size,
                              hipStream_t stream) {
    const int N = in_sizes[0] / 128;
    const int E = in_sizes[1] / 2;
    const float* x = (const float*)d_in[0];
    const int* ei = (const int*)d_in[1];
    const float* W1 = (const float*)d_in[2];
    const float* atS1 = (const float*)d_in[3];
    const float* atD1 = (const float*)d_in[4];
    const float* b1 = (const float*)d_in[5];
    const float* W2 = (const float*)d_in[6];
    const float* atS2 = (const float*)d_in[7];
    const float* atD2 = (const float*)d_in[8];
    const float* b2 = (const float*)d_in[9];
    float* out = (float*)d_out;

    char* ws = (char*)d_ws;
    size_t off = 0;
    auto alloc = [&](size_t bytes) {
        void* p = ws + off;
        off = (off + bytes + 255) & ~(size_t)255;
        return p;
    };
    unsigned int* gmax = (unsigned int*)alloc(8 * sizeof(unsigned int)); // [layer][pos]
    int* cnt_priv = (int*)alloc((size_t)NS * N * 4);
    int* deg = (int*)alloc((size_t)N * 4);
    int* rowptr = (int*)alloc((size_t)(N + 1) * 4);
    int* bsum = (int*)alloc(256 * 4);
    int* boff = (int*)alloc(256 * 4);
    uint4* esd = (uint4*)alloc((size_t)E * 16);
    unsigned short* hb = (unsigned short*)alloc((size_t)N * 128 * 2);  // packed bf16
    float* av_s = (float*)alloc((size_t)N * 4 * 4);
    float* av_d = (float*)alloc((size_t)N * 4 * 4);
    float* x2 = (float*)alloc((size_t)N * 32 * 4);

    const int* e_src = ei;
    const int* e_dst = ei + E;

    const int gemmGrid = (N + 63) / 64;
    const int nodeGrid = (N + 7) / 8;
    const int npb = (N + NB - 1) / NB;       // nodes per bucket (<= MAXNPB)
    const int scanGrid = (N + 255) / 256;    // must be <= 256
    const int bsGrid = NB * NS;              // bucket x slice blocks

    (void)hipMemsetAsync(gmax, 0, 8 * sizeof(unsigned int), stream);

    // CSR build (hist/scan); scatter deferred until after gemm1 (fused q).
    hist_kernel<<<bsGrid, 256, 0, stream>>>(e_dst, cnt_priv, E, N, npb);
    scan_part<<<scanGrid, 256, 0, stream>>>(cnt_priv, deg, bsum, N);
    scan_mid<<<1, 256, 0, stream>>>(bsum, boff, scanGrid, rowptr, N);
    scan_final<<<scanGrid, 256, 0, stream>>>(deg, boff, rowptr, N);

    // layer 1
    gemm_kernel<128><<<gemmGrid, 256, 0, stream>>>(
        x, W1, atS1, atD1, hb, av_s, av_d, gmax, N);
    scatter_kernel<<<bsGrid, 256, 0, stream>>>(
        e_src, e_dst, rowptr, cnt_priv, av_s, av_d, gmax, esd, E, N, npb);
    node_kernel<<<nodeGrid, 256, 0, stream>>>(rowptr, esd, hb, av_s, av_d, gmax,
                                              b1, x2, N, 1);
    // layer 2
    gemm_kernel<32><<<gemmGrid, 256, 0, stream>>>(
        x2, W2, atS2, atD2, hb, av_s, av_d, gmax + 4, N);
    edge_w_kernel<<<2048, 256, 0, stream>>>(esd, av_s, av_d, gmax + 4, E);
    node_kernel<<<nodeGrid, 256, 0, stream>>>(rowptr, esd, hb, av_s, av_d, gmax + 4,
                                              b2, out, N, 0);
}

// Round 14
// 330.288 us; speedup vs baseline: 1.3172x; 1.1064x over previous
//
#include <hip/hip_runtime.h>
#include <hip/hip_bf16.h>
#include <hip/hip_fp16.h>
#include <math.h>

// ---------------------------------------------------------------------------
// 2-layer GAT (PyG GATConv, concat=False, add_self_loops=True) on MI355X.
// R14: CSR-build traffic cut — NB=4 buckets (halves redundant edge-list
// reads), cnt_priv stored as u16 (halves seed/scan traffic), hist/scatter at
// 512 threads (8 waves/CU). Node kernel: 32-lane/node, 4 heads in-lane.
// Unified 16B edge record {src16,dst16,q01,q23}; zero per-edge device atomics.
// ---------------------------------------------------------------------------

#define NS 64         // edge slices
#define NB 4          // node buckets
#define MAXNPB 12500  // max nodes per bucket (N <= 50000)

__device__ __forceinline__ float lrelu(float x) { return x > 0.f ? x : 0.2f * x; }

__device__ __forceinline__ unsigned int fenc(float f) {
    unsigned int u = __float_as_uint(f);
    return (u & 0x80000000u) ? ~u : (u | 0x80000000u);
}
__device__ __forceinline__ float fdec(unsigned int e) {
    unsigned int u = (e & 0x80000000u) ? (e & 0x7FFFFFFFu) : ~e;
    return __uint_as_float(u);
}

__device__ __forceinline__ unsigned short f2bf(float x) {
    unsigned u = __float_as_uint(x);
    return (unsigned short)((u + 0x7FFFu + ((u >> 16) & 1u)) >> 16);
}
__device__ __forceinline__ float bflo(unsigned w) { return __uint_as_float(w << 16); }
__device__ __forceinline__ float bfhi(unsigned w) { return __uint_as_float(w & 0xFFFF0000u); }

__device__ __forceinline__ unsigned pack_h2(float a, float b) {
    const __half2 h = __float22half2_rn(make_float2(a, b));
    return *(const unsigned*)&h;
}
__device__ __forceinline__ float2 unpack_h2(unsigned w) {
    __half2 h = *(const __half2*)&w;
    return __half22float2(h);
}

// ---------------- hist: bucket x slice, LDS-private, no global atomics -----
__global__ __launch_bounds__(512) void hist_kernel(
    const int* __restrict__ dst, unsigned short* __restrict__ cnt_priv,
    int E, int n, int npb) {
    __shared__ int h[MAXNPB];
    const int b = blockIdx.x & (NB - 1);
    const int s = blockIdx.x / NB;
    const int lo = b * npb;
    const int hi = min(lo + npb, n);
    const int span = hi - lo;
    if (span <= 0) return;
    for (int j = threadIdx.x; j < span; j += 512) h[j] = 0;
    __syncthreads();
    const int E4 = E >> 2;
    const int len4 = (E4 + NS - 1) / NS;
    const int beg4 = s * len4;
    const int end4 = min(beg4 + len4, E4);
    const int4* dst4 = (const int4*)dst;
    for (int i = beg4 + threadIdx.x; i < end4; i += 512) {
        const int4 d = dst4[i];
        if (d.x >= lo && d.x < hi) atomicAdd(&h[d.x - lo], 1);
        if (d.y >= lo && d.y < hi) atomicAdd(&h[d.y - lo], 1);
        if (d.z >= lo && d.z < hi) atomicAdd(&h[d.z - lo], 1);
        if (d.w >= lo && d.w < hi) atomicAdd(&h[d.w - lo], 1);
    }
    if (s == NS - 1) {
        for (int i = (E4 << 2) + threadIdx.x; i < E; i += 512) {
            const int d = dst[i];
            if (d >= lo && d < hi) atomicAdd(&h[d - lo], 1);
        }
    }
    __syncthreads();
    unsigned short* outp = cnt_priv + (size_t)s * n + lo;
    for (int j = threadIdx.x; j < span; j += 512) outp[j] = (unsigned short)h[j];
}

// ---------------- scan stage 1: slice prefix (in place, u16) + block sums --
__global__ __launch_bounds__(256) void scan_part(unsigned short* __restrict__ cnt_priv,
                                                 int* __restrict__ deg,
                                                 int* __restrict__ bsum, int n) {
    __shared__ int red[256];
    const int t = threadIdx.x;
    const int node = blockIdx.x * 256 + t;
    int run = 0;
    if (node < n) {
#pragma unroll 4
        for (int s = 0; s < NS; ++s) {
            unsigned short* p = &cnt_priv[(size_t)s * n + node];
            const int c = *p;
            *p = (unsigned short)run;   // exclusive prefix over slices
            run += c;
        }
        deg[node] = run;
    }
    red[t] = (node < n) ? run : 0;
    __syncthreads();
    for (int o = 128; o > 0; o >>= 1) {
        if (t < o) red[t] += red[t + o];
        __syncthreads();
    }
    if (t == 0) bsum[blockIdx.x] = red[0];
}

__global__ __launch_bounds__(256) void scan_mid(const int* __restrict__ bsum,
                                                int* __restrict__ boff, int nb,
                                                int* __restrict__ rowptr, int n) {
    __shared__ int s[256];
    const int t = threadIdx.x;
    const int v = (t < nb) ? bsum[t] : 0;
    s[t] = v;
    __syncthreads();
    for (int o = 1; o < 256; o <<= 1) {
        const int u = (t >= o) ? s[t - o] : 0;
        __syncthreads();
        s[t] += u;
        __syncthreads();
    }
    if (t < nb) boff[t] = s[t] - v;   // exclusive block offset
    if (t == 255) rowptr[n] = s[255]; // total
}

__global__ __launch_bounds__(256) void scan_final(const int* __restrict__ deg,
                                                  const int* __restrict__ boff,
                                                  int* __restrict__ rowptr, int n) {
    __shared__ int s[256];
    const int t = threadIdx.x;
    const int i = blockIdx.x * 256 + t;
    const int v = (i < n) ? deg[i] : 0;
    s[t] = v;
    __syncthreads();
    for (int o = 1; o < 256; o <<= 1) {
        const int u = (t >= o) ? s[t - o] : 0;
        __syncthreads();
        s[t] += u;
        __syncthreads();
    }
    if (i < n) rowptr[i] = boff[blockIdx.x] + s[t] - v;
}

// ---------------- scatter + layer-1 edge weights (fused) -------------------
// LDS cursor seeded from rowptr+cnt_priv (no device atomics). Record:
// esd[p] = { src*16, dst*16, half2(q_pos0,q_pos1), half2(q_pos2,q_pos3) }.
__global__ __launch_bounds__(512) void scatter_kernel(
    const int* __restrict__ src, const int* __restrict__ dst,
    const int* __restrict__ rowptr, const unsigned short* __restrict__ cnt_priv,
    const float* __restrict__ asrc, const float* __restrict__ adst,
    const unsigned int* __restrict__ gmax,
    uint4* __restrict__ esd, int E, int n, int npb) {
    __shared__ int cur[MAXNPB];
    const int b = blockIdx.x & (NB - 1);
    const int s = blockIdx.x / NB;
    const int lo = b * npb;
    const int hi = min(lo + npb, n);
    const int span = hi - lo;
    if (span <= 0) return;
    {
        const unsigned short* cp = cnt_priv + (size_t)s * n + lo;
        const int* rp = rowptr + lo;
        for (int j = threadIdx.x; j < span; j += 512) cur[j] = rp[j] + (int)cp[j];
    }
    __syncthreads();
    const char* aB = (const char*)asrc;
    const char* dB = (const char*)adst;
    const float g0 = fdec(gmax[0]), g1 = fdec(gmax[1]);
    const float g2 = fdec(gmax[2]), g3 = fdec(gmax[3]);

    auto place = [&](int sv, int dv) {
        const int p = atomicAdd(&cur[dv - lo], 1);
        const unsigned s16 = (unsigned)(sv << 4);
        const unsigned d16 = (unsigned)(dv << 4);
        const float4 as = *(const float4*)(aB + s16);
        const float4 ad = *(const float4*)(dB + d16);
        const float q0 = __expf(lrelu(as.x + ad.x) - lrelu(g0 + ad.x));
        const float q1 = __expf(lrelu(as.y + ad.y) - lrelu(g1 + ad.y));
        const float q2 = __expf(lrelu(as.z + ad.z) - lrelu(g2 + ad.z));
        const float q3 = __expf(lrelu(as.w + ad.w) - lrelu(g3 + ad.w));
        esd[p] = make_uint4(s16, d16, pack_h2(q0, q1), pack_h2(q2, q3));
    };

    const int E4 = E >> 2;
    const int len4 = (E4 + NS - 1) / NS;
    const int beg4 = s * len4;
    const int end4 = min(beg4 + len4, E4);
    const int4* dst4 = (const int4*)dst;
    const int4* src4 = (const int4*)src;
    for (int i = beg4 + threadIdx.x; i < end4; i += 512) {
        const int4 d = dst4[i];
        const int4 sv = src4[i];
        if (d.x >= lo && d.x < hi) place(sv.x, d.x);
        if (d.y >= lo && d.y < hi) place(sv.y, d.y);
        if (d.z >= lo && d.z < hi) place(sv.z, d.z);
        if (d.w >= lo && d.w < hi) place(sv.w, d.w);
    }
    if (s == NS - 1) {
        for (int i = (E4 << 2) + threadIdx.x; i < E; i += 512) {
            const int d = dst[i];
            if (d >= lo && d < hi) place(src[i], d);
        }
    }
}

// ---------------- layer-2 edge weights (rewrite q half of esd) -------------
__global__ __launch_bounds__(256) void edge_w_kernel(
    uint4* __restrict__ esd,
    const float* __restrict__ asrc, const float* __restrict__ adst,
    const unsigned int* __restrict__ gmax, int Etot) {
    const char* aB = (const char*)asrc;
    const char* dB = (const char*)adst;
    const float g0 = fdec(gmax[0]), g1 = fdec(gmax[1]);
    const float g2 = fdec(gmax[2]), g3 = fdec(gmax[3]);
    for (int i = blockIdx.x * blockDim.x + threadIdx.x; i < Etot;
         i += gridDim.x * blockDim.x) {
        const unsigned long long sd =
            __builtin_nontemporal_load((const unsigned long long*)&esd[i]);
        const unsigned s16 = (unsigned)sd;
        const unsigned d16 = (unsigned)(sd >> 32);
        const float4 as = *(const float4*)(aB + s16);
        const float4 ad = *(const float4*)(dB + d16);
        const float q0 = __expf(lrelu(as.x + ad.x) - lrelu(g0 + ad.x));
        const float q1 = __expf(lrelu(as.y + ad.y) - lrelu(g1 + ad.y));
        const float q2 = __expf(lrelu(as.z + ad.z) - lrelu(g2 + ad.z));
        const float q3 = __expf(lrelu(as.w + ad.w) - lrelu(g3 + ad.w));
        const unsigned long long rec =
            ((unsigned long long)pack_h2(q2, q3) << 32) | pack_h2(q0, q1);
        __builtin_nontemporal_store(
            rec, (unsigned long long*)((char*)&esd[i] + 8));
    }
}

// ---------------- GEMM + alpha + global head max ---------------------------
// 64 rows/block, acc[8][4]; k unrolled x4.
// Hb layout (bf16): row*256 + f*8 + hp*4 -> dword = (head hp | head hp+2<<16).
template <int K>
__global__ __launch_bounds__(256) void gemm_kernel(
    const float* __restrict__ X, const float* __restrict__ W,
    const float* __restrict__ AttS, const float* __restrict__ AttD,
    unsigned short* __restrict__ Hb, float* __restrict__ asrc, float* __restrict__ adst,
    unsigned int* __restrict__ gmax, int n) {
    constexpr int KC = 32;
    __shared__ __align__(16) float Ws[KC * 128];
    __shared__ __align__(16) float Xs[64 * K];
    __shared__ unsigned int smax[4];
    const int tid = threadIdx.x;

    const int r = tid >> 5;          // row-in-batch 0..7
    const int sub = tid & 31;
    const int head = sub >> 3;       // 0..3
    const int pos = ((head & 1) << 1) | (head >> 1);  // [0,2,1,3] order
    const int fc = (sub & 7) * 4;    // feat-in-head base
    const int rowBase = blockIdx.x * 64;

    if (tid < 4) smax[tid] = 0u;
    {
        const float4* X4 = (const float4*)X;
        float4* Xs4 = (float4*)Xs;
        const int K4 = K / 4;
        for (int i = tid; i < 64 * K4; i += 256) {
            int rr = rowBase + i / K4;
            Xs4[i] = (rr < n) ? X4[(size_t)rr * K4 + (i % K4)] : make_float4(0.f, 0.f, 0.f, 0.f);
        }
    }

    float acc[8][4] = {};
    const float4* Ws4 = (const float4*)Ws;
    for (int kt = 0; kt < K; kt += KC) {
        __syncthreads();
        {
            const float4* W4 = (const float4*)(W + kt * 128);
            float4* WsS = (float4*)Ws;
#pragma unroll
            for (int i = 0; i < 4; ++i) WsS[tid + i * 256] = W4[tid + i * 256];
        }
        __syncthreads();
#pragma unroll
        for (int k = 0; k < KC; k += 4) {
            float4 wv[4];
#pragma unroll
            for (int j = 0; j < 4; ++j) wv[j] = Ws4[(k + j) * 32 + sub];
            float4 xv[8];
#pragma unroll
            for (int b = 0; b < 8; ++b)
                xv[b] = *(const float4*)&Xs[(b * 8 + r) * K + kt + k];
#pragma unroll
            for (int b = 0; b < 8; ++b) {
                acc[b][0] = fmaf(xv[b].x, wv[0].x, acc[b][0]);
                acc[b][1] = fmaf(xv[b].x, wv[0].y, acc[b][1]);
                acc[b][2] = fmaf(xv[b].x, wv[0].z, acc[b][2]);
                acc[b][3] = fmaf(xv[b].x, wv[0].w, acc[b][3]);
                acc[b][0] = fmaf(xv[b].y, wv[1].x, acc[b][0]);
                acc[b][1] = fmaf(xv[b].y, wv[1].y, acc[b][1]);
                acc[b][2] = fmaf(xv[b].y, wv[1].z, acc[b][2]);
                acc[b][3] = fmaf(xv[b].y, wv[1].w, acc[b][3]);
                acc[b][0] = fmaf(xv[b].z, wv[2].x, acc[b][0]);
                acc[b][1] = fmaf(xv[b].z, wv[2].y, acc[b][1]);
                acc[b][2] = fmaf(xv[b].z, wv[2].z, acc[b][2]);
                acc[b][3] = fmaf(xv[b].z, wv[2].w, acc[b][3]);
                acc[b][0] = fmaf(xv[b].w, wv[3].x, acc[b][0]);
                acc[b][1] = fmaf(xv[b].w, wv[3].y, acc[b][1]);
                acc[b][2] = fmaf(xv[b].w, wv[3].z, acc[b][2]);
                acc[b][3] = fmaf(xv[b].w, wv[3].w, acc[b][3]);
            }
        }
    }

    float a_s[4], a_d[4];
#pragma unroll
    for (int j = 0; j < 4; ++j) {
        a_s[j] = AttS[head * 32 + fc + j];
        a_d[j] = AttD[head * 32 + fc + j];
    }
#pragma unroll
    for (int b = 0; b < 8; ++b) {
        const int row = rowBase + b * 8 + r;
        const float p0 = __shfl_xor(acc[b][0], 16);  // partner head^2, same feats
        const float p1 = __shfl_xor(acc[b][1], 16);
        const float p2 = __shfl_xor(acc[b][2], 16);
        const float p3 = __shfl_xor(acc[b][3], 16);
        if (row < n) {
            if (head < 2) {
                char* base = (char*)Hb + (size_t)row * 256 + (unsigned)fc * 8 + head * 4;
                *(unsigned*)(base + 0)  = (unsigned)f2bf(acc[b][0]) | ((unsigned)f2bf(p0) << 16);
                *(unsigned*)(base + 8)  = (unsigned)f2bf(acc[b][1]) | ((unsigned)f2bf(p1) << 16);
                *(unsigned*)(base + 16) = (unsigned)f2bf(acc[b][2]) | ((unsigned)f2bf(p2) << 16);
                *(unsigned*)(base + 24) = (unsigned)f2bf(acc[b][3]) | ((unsigned)f2bf(p3) << 16);
            }
            float ps = acc[b][0] * a_s[0] + acc[b][1] * a_s[1] +
                       acc[b][2] * a_s[2] + acc[b][3] * a_s[3];
            float pd = acc[b][0] * a_d[0] + acc[b][1] * a_d[1] +
                       acc[b][2] * a_d[2] + acc[b][3] * a_d[3];
#pragma unroll
            for (int msk = 1; msk < 8; msk <<= 1) {
                ps += __shfl_xor(ps, msk);
                pd += __shfl_xor(pd, msk);
            }
            if ((sub & 7) == 0) {
                asrc[row * 4 + pos] = ps;
                adst[row * 4 + pos] = pd;
                atomicMax(&smax[pos], fenc(ps));
            }
        }
    }
    __syncthreads();
    if (tid < 4) atomicMax(&gmax[tid], smax[tid]);
}

// ---------------- per-node aggregate: 32 lanes/node, 4 heads in-lane -------
__global__ __launch_bounds__(256) void node_kernel(
    const int* __restrict__ rowptr, const uint4* __restrict__ esd,
    const unsigned short* __restrict__ Hb, const float* __restrict__ asrc,
    const float* __restrict__ adst, const unsigned int* __restrict__ gmax,
    const float* __restrict__ bias,
    float* __restrict__ outp, int n, int apply_elu) {
    const int node = blockIdx.x * 8 + (threadIdx.x >> 5);
    if (node >= n) return;
    const unsigned f = threadIdx.x & 31;
    const unsigned f8 = f * 8;
    const char* hB = (const char*)Hb;
    const unsigned long long* eB = (const unsigned long long*)esd;

    const int beg = rowptr[node], end = rowptr[node + 1];
    const float4 ad4 = *(const float4*)(adst + (size_t)node * 4);  // pos order
    const float4 as4 = *(const float4*)(asrc + (size_t)node * 4);
    const float M0 = lrelu(fdec(gmax[0]) + ad4.x);
    const float M1 = lrelu(fdec(gmax[1]) + ad4.y);
    const float M2 = lrelu(fdec(gmax[2]) + ad4.z);
    const float M3 = lrelu(fdec(gmax[3]) + ad4.w);

    // self loop
    const float q0 = __expf(lrelu(as4.x + ad4.x) - M0);
    const float q1 = __expf(lrelu(as4.y + ad4.y) - M1);
    const float q2 = __expf(lrelu(as4.z + ad4.z) - M2);
    const float q3 = __expf(lrelu(as4.w + ad4.w) - M3);
    float s0 = q0, s1 = q1, s2 = q2, s3 = q3;
    const uint2 hs = *(const uint2*)(hB + ((size_t)node << 8) + f8);
    float a0 = q0 * bflo(hs.x);   // pos0 = head0
    float a1 = q1 * bfhi(hs.x);   // pos1 = head2
    float a2 = q2 * bflo(hs.y);   // pos2 = head1
    float a3 = q3 * bfhi(hs.y);   // pos3 = head3

    int i = beg;
    for (; i + 8 <= end; i += 8) {
        unsigned long long e0[8], e1[8];
#pragma unroll
        for (int u = 0; u < 8; ++u) {
            e0[u] = __builtin_nontemporal_load(&eB[(size_t)(i + u) * 2]);      // {s16,d16}
            e1[u] = __builtin_nontemporal_load(&eB[(size_t)(i + u) * 2 + 1]);  // {q01,q23}
        }
        uint2 h[8];
#pragma unroll
        for (int u = 0; u < 8; ++u)
            h[u] = *(const uint2*)(hB + (((unsigned)e0[u]) << 4) + f8);
#pragma unroll
        for (int u = 0; u < 8; ++u) {
            const float2 qa = unpack_h2((unsigned)e1[u]);
            const float2 qb = unpack_h2((unsigned)(e1[u] >> 32));
            s0 += qa.x; s1 += qa.y; s2 += qb.x; s3 += qb.y;
            a0 = fmaf(qa.x, bflo(h[u].x), a0);
            a1 = fmaf(qa.y, bfhi(h[u].x), a1);
            a2 = fmaf(qb.x, bflo(h[u].y), a2);
            a3 = fmaf(qb.y, bfhi(h[u].y), a3);
        }
    }
    for (; i < end; ++i) {
        const unsigned long long e0 = __builtin_nontemporal_load(&eB[(size_t)i * 2]);
        const unsigned long long e1 = __builtin_nontemporal_load(&eB[(size_t)i * 2 + 1]);
        const uint2 h = *(const uint2*)(hB + (((unsigned)e0) << 4) + f8);
        const float2 qa = unpack_h2((unsigned)e1);
        const float2 qb = unpack_h2((unsigned)(e1 >> 32));
        s0 += qa.x; s1 += qa.y; s2 += qb.x; s3 += qb.y;
        a0 = fmaf(qa.x, bflo(h.x), a0);
        a1 = fmaf(qa.y, bfhi(h.x), a1);
        a2 = fmaf(qb.x, bflo(h.y), a2);
        a3 = fmaf(qb.y, bfhi(h.y), a3);
    }

    float v = a0 / s0 + a1 / s1 + a2 / s2 + a3 / s3;
    v = v * 0.25f + bias[f];
    if (apply_elu) v = (v > 0.f) ? v : (__expf(v) - 1.f);
    outp[(size_t)node * 32 + f] = v;
}

// ---------------- launch ----------------

extern "C" void kernel_launch(void* const* d_in, const int* in_sizes, int n_in,
                              void* d_out, int out_size, void* d_ws, size_t ws_size,
                              hipStream_t stream) {
    const int N = in_sizes[0] / 128;
    const int E = in_sizes[1] / 2;
    const float* x = (const float*)d_in[0];
    const int* ei = (const int*)d_in[1];
    const float* W1 = (const float*)d_in[2];
    const float* atS1 = (const float*)d_in[3];
    const float* atD1 = (const float*)d_in[4];
    const float* b1 = (const float*)d_in[5];
    const float* W2 = (const float*)d_in[6];
    const float* atS2 = (const float*)d_in[7];
    const float* atD2 = (const float*)d_in[8];
    const float* b2 = (const float*)d_in[9];
    float* out = (float*)d_out;

    char* ws = (char*)d_ws;
    size_t off = 0;
    auto alloc = [&](size_t bytes) {
        void* p = ws + off;
        off = (off + bytes + 255) & ~(size_t)255;
        return p;
    };
    unsigned int* gmax = (unsigned int*)alloc(8 * sizeof(unsigned int)); // [layer][pos]
    unsigned short* cnt_priv = (unsigned short*)alloc((size_t)NS * N * 2);
    int* deg = (int*)alloc((size_t)N * 4);
    int* rowptr = (int*)alloc((size_t)(N + 1) * 4);
    int* bsum = (int*)alloc(256 * 4);
    int* boff = (int*)alloc(256 * 4);
    uint4* esd = (uint4*)alloc((size_t)E * 16);
    unsigned short* hb = (unsigned short*)alloc((size_t)N * 128 * 2);  // packed bf16
    float* av_s = (float*)alloc((size_t)N * 4 * 4);
    float* av_d = (float*)alloc((size_t)N * 4 * 4);
    float* x2 = (float*)alloc((size_t)N * 32 * 4);

    const int* e_src = ei;
    const int* e_dst = ei + E;

    const int gemmGrid = (N + 63) / 64;
    const int nodeGrid = (N + 7) / 8;
    const int npb = (N + NB - 1) / NB;       // nodes per bucket (<= MAXNPB)
    const int scanGrid = (N + 255) / 256;    // must be <= 256
    const int bsGrid = NB * NS;              // bucket x slice blocks

    (void)hipMemsetAsync(gmax, 0, 8 * sizeof(unsigned int), stream);

    // CSR build (hist/scan); scatter deferred until after gemm1 (fused q).
    hist_kernel<<<bsGrid, 512, 0, stream>>>(e_dst, cnt_priv, E, N, npb);
    scan_part<<<scanGrid, 256, 0, stream>>>(cnt_priv, deg, bsum, N);
    scan_mid<<<1, 256, 0, stream>>>(bsum, boff, scanGrid, rowptr, N);
    scan_final<<<scanGrid, 256, 0, stream>>>(deg, boff, rowptr, N);

    // layer 1
    gemm_kernel<128><<<gemmGrid, 256, 0, stream>>>(
        x, W1, atS1, atD1, hb, av_s, av_d, gmax, N);
    scatter_kernel<<<bsGrid, 512, 0, stream>>>(
        e_src, e_dst, rowptr, cnt_priv, av_s, av_d, gmax, esd, E, N, npb);
    node_kernel<<<nodeGrid, 256, 0, stream>>>(rowptr, esd, hb, av_s, av_d, gmax,
                                              b1, x2, N, 1);
    // layer 2
    gemm_kernel<32><<<gemmGrid, 256, 0, stream>>>(
        x2, W2, atS2, atD2, hb, av_s, av_d, gmax + 4, N);
    edge_w_kernel<<<2048, 256, 0, stream>>>(esd, av_s, av_d, gmax + 4, E);
    node_kernel<<<nodeGrid, 256, 0, stream>>>(rowptr, esd, hb, av_s, av_d, gmax + 4,
                                              b2, out, N, 0);
}